// Round 14
// baseline (431.363 us; speedup 1.0000x reference)
//
#include <hip/hip_runtime.h>
#include <hip/hip_bf16.h>
#include <hip/hip_cooperative_groups.h>

namespace cg = cooperative_groups;

#define CRF_B 1024
#define CRF_T 512
#define CRF_C 32
#define WARM  4    // validated round 12/13 (absmax 16.0)
#define FSL   8    // fused-path segment length
#define FSEG  (CRF_T / FSL)   // 64 segments

typedef float f32x4 __attribute__((ext_vector_type(4)));
typedef short s16x8 __attribute__((ext_vector_type(8)));

static __device__ __forceinline__ unsigned f2bf(float f) {
    union { float f; unsigned u; } v; v.f = f;
    return (v.u + 0x7FFFu + ((v.u >> 16) & 1u)) >> 16;
}

#define CVT_PK(dst, lo, hi) \
    asm("v_cvt_pk_bf16_f32 %0, %1, %2" : "=v"(dst) : "v"(lo), "v"(hi))
#define SWAP32(a, b) \
    asm("v_permlane32_swap_b32 %0, %1" : "+v"(a), "+v"(b))
#define SWAP16(a, b) \
    asm("v_permlane16_swap_b32 %0, %1" : "+v"(a), "+v"(b))

#define MAKE_AFRAGS()                                                          \
    s16x8 A0, A1;                                                              \
    _Pragma("unroll")                                                          \
    for (int e = 0; e < 8; ++e) {                                              \
        int k_ = h * 8 + e;                                                    \
        A0[e] = (short)f2bf(__expf(trans[r * CRF_C + k_]));                    \
        A1[e] = (short)f2bf(__expf(trans[(16 + r) * CRF_C + k_]));             \
    }

#define LOADSLOT(PL_, PH_, TT_)                                                \
    { const float* pa_ = xb + (size_t)(TT_) * CRF_C;                           \
      PL_ = *(const f32x4*)(pa_ + 4 * h);                                      \
      PH_ = *(const f32x4*)(pa_ + 16 + 4 * h); }

// ============================================================================
// FUSED (cooperative): one kernel. Wave handles one (b-group, segment).
// Phase 1 (seam+spec-write): s=0 exact from t=0 (writes t=0..7 exact);
//   s>0 flat-init at 8s-4, steps k=1..11, writes t=8s..8s+7 as SPEC alphas
//   (= true - c_s), captures v0save (k=WARM-1) and uval (k=nsteps) in regs.
//   All in-loop stores wave-uniform-conditioned (rounds 8/10 NaN rule).
// gg[s][b] = uval - v0save stored agent-scope; __threadfence; grid.sync().
// Phase 2 (fixup): c_s = sum_{sp<s} gg[sp][b] - v0_s (v0 shfl-broadcast);
//   read-modify-write += c_s on own 8 rows (pure BW, own-L2-resident).
// ============================================================================
__global__ __launch_bounds__(128) void crf_fused_kernel(
    const float* __restrict__ x, const float* __restrict__ trans,
    const float* __restrict__ orig, float* gg, float* __restrict__ out)
{
    const int l  = threadIdx.x & 63;
    const int wv = threadIdx.x >> 6;
    const int r  = l & 15;
    const int h  = l >> 4;
    const int b  = blockIdx.x * 16 + r;
    const int s  = blockIdx.y * 2 + wv;

    MAKE_AFRAGS();

    const float* xb = x + (size_t)b * CRF_T * CRF_C;
    const int t_a    = (s == 0) ? 0 : (FSL * s - WARM);
    const int nsteps = (s == 0) ? (FSL - 1) : (FSL + WARM - 1);
    const int tend   = t_a + nsteps;

    // init state at t_a
    float base0;
    f32x4 ab0, ab1;
    {
        const float* row = xb + (size_t)t_a * CRF_C;
        ab0 = *(const f32x4*)(row + 8 * h);
        ab1 = *(const f32x4*)(row + 8 * h + 4);
        if (s == 0) {
            f32x4 ob0 = *(const f32x4*)(orig + 8 * h);
            f32x4 ob1 = *(const f32x4*)(orig + 8 * h + 4);
            #pragma unroll
            for (int i = 0; i < 4; ++i) { ab0[i] += ob0[i]; ab1[i] += ob1[i]; }
            base0 = row[0] + orig[0];
        } else {
            base0 = row[0];
        }
    }
    float A = base0;
    s16x8 Bf;
    {
        unsigned q0, q1, q2, q3;
        CVT_PK(q0, __expf(ab0[0] - base0), __expf(ab0[1] - base0));
        CVT_PK(q1, __expf(ab0[2] - base0), __expf(ab0[3] - base0));
        CVT_PK(q2, __expf(ab1[0] - base0), __expf(ab1[1] - base0));
        CVT_PK(q3, __expf(ab1[2] - base0), __expf(ab1[3] - base0));
        union { unsigned w[4]; s16x8 v; } bu;
        bu.w[0] = q0; bu.w[1] = q1; bu.w[2] = q2; bu.w[3] = q3;
        Bf = bu.v;
    }

    if (s == 0) {   // t = 0 outputs (exact)
        f32x4 xd0 = *(const f32x4*)(xb + 4 * h);
        f32x4 xd1 = *(const f32x4*)(xb + 16 + 4 * h);
        f32x4 od0 = *(const f32x4*)(orig + 4 * h);
        f32x4 od1 = *(const f32x4*)(orig + 16 + 4 * h);
        f32x4 a00, a01;
        #pragma unroll
        for (int i = 0; i < 4; ++i) { a00[i] = xd0[i] + od0[i]; a01[i] = xd1[i] + od1[i]; }
        *(f32x4*)(out + (size_t)b * CRF_C + 4 * h) = a00;
        *(f32x4*)(out + (size_t)b * CRF_C + 16 + 4 * h) = a01;
    }

    f32x4 pl0, pl1, pl2, pl3, qh0, qh1, qh2, qh3;
    LOADSLOT(pl0, qh0, t_a + 1) LOADSLOT(pl1, qh1, t_a + 2)
    LOADSLOT(pl2, qh2, t_a + 3) LOADSLOT(pl3, qh3, t_a + 4)

    const f32x4 zz4 = {0.f, 0.f, 0.f, 0.f};
    int t = t_a + 1, k = 1;
    float uval = 0.0f, v0save = 0.0f;
    float* op0 = out + ((size_t)(t_a + 1) * CRF_B + b) * CRF_C + 4 * h;

#define FSTEP(PL_, PH_)                                                        \
    {                                                                          \
        f32x4 xl = PL_, xh = PH_;                                              \
        { int tn_ = t + 4; if (tn_ > tend) tn_ = tend;                         \
          LOADSLOT(PL_, PH_, tn_) }                                            \
        f32x4 D0 = __builtin_amdgcn_mfma_f32_16x16x32_bf16(A0, Bf, zz4, 0, 0, 0); \
        f32x4 D1 = __builtin_amdgcn_mfma_f32_16x16x32_bf16(A1, Bf, zz4, 0, 0, 0); \
        int ex = (int)((__float_as_uint(D0[0]) >> 23) & 0xFFu) - 127;          \
        ex = __shfl(ex, r, 64);                                                \
        float me = (float)ex;                                                  \
        float Aent = A;                                                        \
        A = Aent + me * 0.69314718055994530942f;                               \
        float f0 = exp2f(fmaf(xl[0], 1.44269504088896f, -me));                 \
        float f1 = exp2f(fmaf(xl[1], 1.44269504088896f, -me));                 \
        float f2 = exp2f(fmaf(xl[2], 1.44269504088896f, -me));                 \
        float f3 = exp2f(fmaf(xl[3], 1.44269504088896f, -me));                 \
        float g0 = exp2f(fmaf(xh[0], 1.44269504088896f, -me));                 \
        float g1 = exp2f(fmaf(xh[1], 1.44269504088896f, -me));                 \
        float g2 = exp2f(fmaf(xh[2], 1.44269504088896f, -me));                 \
        float g3 = exp2f(fmaf(xh[3], 1.44269504088896f, -me));                 \
        if ((s != 0) && (k == WARM - 1))                                       \
            v0save = xl[0] + Aent + __logf(D0[0]);  /* reg only, uniform */    \
        if ((s == 0) || (k >= WARM)) {       /* wave-uniform spec write */     \
            f32x4 alo, ahi;                                                    \
            alo[0] = xl[0] + Aent + __logf(D0[0]);                             \
            alo[1] = xl[1] + Aent + __logf(D0[1]);                             \
            alo[2] = xl[2] + Aent + __logf(D0[2]);                             \
            alo[3] = xl[3] + Aent + __logf(D0[3]);                             \
            ahi[0] = xh[0] + Aent + __logf(D1[0]);                             \
            ahi[1] = xh[1] + Aent + __logf(D1[1]);                             \
            ahi[2] = xh[2] + Aent + __logf(D1[2]);                             \
            ahi[3] = xh[3] + Aent + __logf(D1[3]);                             \
            *(f32x4*)op0 = alo;                                                \
            *(f32x4*)(op0 + 16) = ahi;                                         \
            if (k == nsteps) uval = alo[0];                                    \
        }                                                                      \
        op0 += (size_t)CRF_B * CRF_C;                                          \
        unsigned w0, w1, w2, w3;                                               \
        CVT_PK(w0, D0[0] * f0, D0[1] * f1);                                    \
        CVT_PK(w1, D0[2] * f2, D0[3] * f3);                                    \
        CVT_PK(w2, D1[0] * g0, D1[1] * g1);                                    \
        CVT_PK(w3, D1[2] * g2, D1[3] * g3);                                    \
        SWAP32(w0, w2); SWAP16(w0, w2);                                        \
        SWAP32(w1, w3); SWAP16(w1, w3);                                        \
        {                                                                      \
            union { unsigned w[4]; s16x8 v; } bu_;                             \
            bu_.w[0] = w0; bu_.w[1] = w1; bu_.w[2] = w2; bu_.w[3] = w3;        \
            Bf = bu_.v;                                                        \
        }                                                                      \
        ++t; ++k;                                                              \
    }

    const int ngr = nsteps >> 2;    // 7 or 11, both == 3 (mod 4)
    for (int g = 0; g < ngr; ++g) {
        FSTEP(pl0, qh0) FSTEP(pl1, qh1) FSTEP(pl2, qh2) FSTEP(pl3, qh3)
    }
    FSTEP(pl0, qh0) FSTEP(pl1, qh1) FSTEP(pl2, qh2)
#undef FSTEP

    // gg store (h==0, outside loop), agent scope for cross-XCD visibility
    if (h == 0)
        __hip_atomic_store(&gg[(size_t)s * CRF_B + b], uval - v0save,
                           __ATOMIC_RELAXED, __HIP_MEMORY_SCOPE_AGENT);
    __threadfence();
    cg::this_grid().sync();

    // ---- phase 2: fixup ----
    if (s != 0) {
        float* gb = gg + b;
        float c0 = 0.f, c1 = 0.f, c2 = 0.f, c3 = 0.f;
        int sp = 0;
        for (; sp + 4 <= s; sp += 4) {
            c0 += __hip_atomic_load(&gb[(size_t)(sp)     * CRF_B], __ATOMIC_RELAXED, __HIP_MEMORY_SCOPE_AGENT);
            c1 += __hip_atomic_load(&gb[(size_t)(sp + 1) * CRF_B], __ATOMIC_RELAXED, __HIP_MEMORY_SCOPE_AGENT);
            c2 += __hip_atomic_load(&gb[(size_t)(sp + 2) * CRF_B], __ATOMIC_RELAXED, __HIP_MEMORY_SCOPE_AGENT);
            c3 += __hip_atomic_load(&gb[(size_t)(sp + 3) * CRF_B], __ATOMIC_RELAXED, __HIP_MEMORY_SCOPE_AGENT);
        }
        for (; sp < s; ++sp)
            c0 += __hip_atomic_load(&gb[(size_t)sp * CRF_B], __ATOMIC_RELAXED, __HIP_MEMORY_SCOPE_AGENT);
        float v0b = __shfl(v0save, r, 64);      // j=0 row lives on h==0 lane r
        float cs = ((c0 + c1) + (c2 + c3)) - v0b;

        float* op = out + ((size_t)(FSL * s) * CRF_B + b) * CRF_C + 4 * h;
        #pragma unroll
        for (int q = 0; q < FSL; ++q) {
            f32x4 va = *(const f32x4*)op;
            f32x4 vb = *(const f32x4*)(op + 16);
            #pragma unroll
            for (int i = 0; i < 4; ++i) { va[i] += cs; vb[i] += cs; }
            *(f32x4*)op = va;
            *(f32x4*)(op + 16) = vb;
            op += (size_t)CRF_B * CRF_C;
        }
    }
}

// ============================================================================
// Round-13 validated 2-kernel path (fallback if cooperative launch fails)
// ============================================================================
template <int SL>
__global__ __launch_bounds__(64) void crf_seam_kernel(
    const float* __restrict__ x, const float* __restrict__ trans,
    const float* __restrict__ orig, float* __restrict__ snap,
    float* __restrict__ gg)
{
    const int SEG_S = CRF_T / SL;
    const int l = threadIdx.x;
    const int r = l & 15;
    const int h = l >> 4;
    const int b = blockIdx.x * 16 + r;
    const int s = blockIdx.y;

    MAKE_AFRAGS();

    const float* xb = x + (size_t)b * CRF_T * CRF_C;
    const int t_a    = (s == 0) ? 0 : (SL * s - WARM);
    const int nsteps = (s == 0) ? (SL - 1) : (SL + WARM - 1);
    const int tend   = t_a + nsteps;

    float base0;
    f32x4 ab0, ab1;
    {
        const float* row = xb + (size_t)t_a * CRF_C;
        ab0 = *(const f32x4*)(row + 8 * h);
        ab1 = *(const f32x4*)(row + 8 * h + 4);
        if (s == 0) {
            f32x4 ob0 = *(const f32x4*)(orig + 8 * h);
            f32x4 ob1 = *(const f32x4*)(orig + 8 * h + 4);
            #pragma unroll
            for (int i = 0; i < 4; ++i) { ab0[i] += ob0[i]; ab1[i] += ob1[i]; }
            base0 = row[0] + orig[0];
        } else {
            base0 = row[0];
        }
    }
    float A = base0;
    s16x8 Bf;
    {
        unsigned q0, q1, q2, q3;
        CVT_PK(q0, __expf(ab0[0] - base0), __expf(ab0[1] - base0));
        CVT_PK(q1, __expf(ab0[2] - base0), __expf(ab0[3] - base0));
        CVT_PK(q2, __expf(ab1[0] - base0), __expf(ab1[1] - base0));
        CVT_PK(q3, __expf(ab1[2] - base0), __expf(ab1[3] - base0));
        union { unsigned w[4]; s16x8 v; } bu;
        bu.w[0] = q0; bu.w[1] = q1; bu.w[2] = q2; bu.w[3] = q3;
        Bf = bu.v;
    }

    f32x4 pl0, pl1, pl2, pl3, qh0, qh1, qh2, qh3;
    LOADSLOT(pl0, qh0, t_a + 1) LOADSLOT(pl1, qh1, t_a + 2)
    LOADSLOT(pl2, qh2, t_a + 3) LOADSLOT(pl3, qh3, t_a + 4)

    const f32x4 zz4 = {0.f, 0.f, 0.f, 0.f};
    int t = t_a + 1, k = 1;
    float uval = 0.0f;
    float v0save = 0.0f;
    float* vrow = snap + ((size_t)b * SEG_S + s) * CRF_C;

#define PSTEP(PL_, PH_)                                                        \
    {                                                                          \
        f32x4 xl = PL_, xh = PH_;                                              \
        { int tn_ = t + 4; if (tn_ > tend) tn_ = tend;                         \
          LOADSLOT(PL_, PH_, tn_) }                                            \
        f32x4 D0 = __builtin_amdgcn_mfma_f32_16x16x32_bf16(A0, Bf, zz4, 0, 0, 0); \
        f32x4 D1 = __builtin_amdgcn_mfma_f32_16x16x32_bf16(A1, Bf, zz4, 0, 0, 0); \
        int ex = (int)((__float_as_uint(D0[0]) >> 23) & 0xFFu) - 127;          \
        ex = __shfl(ex, r, 64);                                                \
        float me = (float)ex;                                                  \
        float Aent = A;                                                        \
        A = Aent + me * 0.69314718055994530942f;                               \
        float f0 = exp2f(fmaf(xl[0], 1.44269504088896f, -me));                 \
        float f1 = exp2f(fmaf(xl[1], 1.44269504088896f, -me));                 \
        float f2 = exp2f(fmaf(xl[2], 1.44269504088896f, -me));                 \
        float f3 = exp2f(fmaf(xl[3], 1.44269504088896f, -me));                 \
        float g0 = exp2f(fmaf(xh[0], 1.44269504088896f, -me));                 \
        float g1 = exp2f(fmaf(xh[1], 1.44269504088896f, -me));                 \
        float g2 = exp2f(fmaf(xh[2], 1.44269504088896f, -me));                 \
        float g3 = exp2f(fmaf(xh[3], 1.44269504088896f, -me));                 \
        if ((s != 0) && (k == WARM - 1)) {                                     \
            f32x4 vlo, vhi;                                                    \
            vlo[0] = xl[0] + Aent + __logf(D0[0]);                             \
            vlo[1] = xl[1] + Aent + __logf(D0[1]);                             \
            vlo[2] = xl[2] + Aent + __logf(D0[2]);                             \
            vlo[3] = xl[3] + Aent + __logf(D0[3]);                             \
            vhi[0] = xh[0] + Aent + __logf(D1[0]);                             \
            vhi[1] = xh[1] + Aent + __logf(D1[1]);                             \
            vhi[2] = xh[2] + Aent + __logf(D1[2]);                             \
            vhi[3] = xh[3] + Aent + __logf(D1[3]);                             \
            *(f32x4*)(vrow + 4 * h) = vlo;                                     \
            *(f32x4*)(vrow + 16 + 4 * h) = vhi;                                \
            v0save = vlo[0];                                                   \
        }                                                                      \
        if (k == nsteps) uval = xl[0] + Aent + __logf(D0[0]);                  \
        unsigned w0, w1, w2, w3;                                               \
        CVT_PK(w0, D0[0] * f0, D0[1] * f1);                                    \
        CVT_PK(w1, D0[2] * f2, D0[3] * f3);                                    \
        CVT_PK(w2, D1[0] * g0, D1[1] * g1);                                    \
        CVT_PK(w3, D1[2] * g2, D1[3] * g3);                                    \
        SWAP32(w0, w2); SWAP16(w0, w2);                                        \
        SWAP32(w1, w3); SWAP16(w1, w3);                                        \
        {                                                                      \
            union { unsigned w[4]; s16x8 v; } bu_;                             \
            bu_.w[0] = w0; bu_.w[1] = w1; bu_.w[2] = w2; bu_.w[3] = w3;        \
            Bf = bu_.v;                                                        \
        }                                                                      \
        ++t; ++k;                                                              \
    }

    const int ngr = nsteps >> 2;
    for (int g = 0; g < ngr; ++g) {
        PSTEP(pl0, qh0) PSTEP(pl1, qh1) PSTEP(pl2, qh2) PSTEP(pl3, qh3)
    }
    PSTEP(pl0, qh0) PSTEP(pl1, qh1) PSTEP(pl2, qh2)
#undef PSTEP

    if (h == 0) gg[(size_t)s * CRF_B + b] = uval - v0save;
}

template <int SL>
__global__ __launch_bounds__(64) void crf_out_kernel(
    const float* __restrict__ x, const float* __restrict__ trans,
    const float* __restrict__ orig, const float* __restrict__ snap,
    const float* __restrict__ gg, float* __restrict__ out)
{
    const int SEG_S = CRF_T / SL;
    const int l = threadIdx.x;
    const int r = l & 15;
    const int h = l >> 4;
    const int b = blockIdx.x * 16 + r;
    const int s = blockIdx.y;

    MAKE_AFRAGS();

    const float* xb = x + (size_t)b * CRF_T * CRF_C;

    int t0, nst;
    float s0;
    s16x8 Bf;
    if (s == 0) {
        t0 = 1; nst = SL - 1;
        s0 = xb[0] + orig[0];
        f32x4 ib0 = *(const f32x4*)(xb + 8 * h);
        f32x4 ib1 = *(const f32x4*)(xb + 8 * h + 4);
        f32x4 ob0 = *(const f32x4*)(orig + 8 * h);
        f32x4 ob1 = *(const f32x4*)(orig + 8 * h + 4);
        unsigned q0, q1, q2, q3;
        CVT_PK(q0, __expf(ib0[0] + ob0[0] - s0), __expf(ib0[1] + ob0[1] - s0));
        CVT_PK(q1, __expf(ib0[2] + ob0[2] - s0), __expf(ib0[3] + ob0[3] - s0));
        CVT_PK(q2, __expf(ib1[0] + ob1[0] - s0), __expf(ib1[1] + ob1[1] - s0));
        CVT_PK(q3, __expf(ib1[2] + ob1[2] - s0), __expf(ib1[3] + ob1[3] - s0));
        union { unsigned w[4]; s16x8 v; } bu;
        bu.w[0] = q0; bu.w[1] = q1; bu.w[2] = q2; bu.w[3] = q3;
        Bf = bu.v;
        f32x4 xd0 = *(const f32x4*)(xb + 4 * h);
        f32x4 xd1 = *(const f32x4*)(xb + 16 + 4 * h);
        f32x4 od0 = *(const f32x4*)(orig + 4 * h);
        f32x4 od1 = *(const f32x4*)(orig + 16 + 4 * h);
        f32x4 a00, a01;
        #pragma unroll
        for (int i = 0; i < 4; ++i) { a00[i] = xd0[i] + od0[i]; a01[i] = xd1[i] + od1[i]; }
        *(f32x4*)(out + (size_t)b * CRF_C + 4 * h) = a00;
        *(f32x4*)(out + (size_t)b * CRF_C + 16 + 4 * h) = a01;
    } else {
        t0 = SL * s; nst = SL;
        const float* gb = gg + b;
        float c0 = 0.f, c1 = 0.f, c2 = 0.f, c3 = 0.f;
        int sp = 0;
        for (; sp + 4 <= s; sp += 4) {
            c0 += gb[(size_t)(sp)     * CRF_B];
            c1 += gb[(size_t)(sp + 1) * CRF_B];
            c2 += gb[(size_t)(sp + 2) * CRF_B];
            c3 += gb[(size_t)(sp + 3) * CRF_B];
        }
        for (; sp < s; ++sp) c0 += gb[(size_t)sp * CRF_B];
        s0 = (c0 + c1) + (c2 + c3);

        const float* vp = snap + ((size_t)b * SEG_S + s) * CRF_C;
        const float vp0 = vp[0];
        f32x4 vb0 = *(const f32x4*)(vp + 8 * h);
        f32x4 vb1 = *(const f32x4*)(vp + 8 * h + 4);
        unsigned q0, q1, q2, q3;
        CVT_PK(q0, __expf(vb0[0] - vp0), __expf(vb0[1] - vp0));
        CVT_PK(q1, __expf(vb0[2] - vp0), __expf(vb0[3] - vp0));
        CVT_PK(q2, __expf(vb1[0] - vp0), __expf(vb1[1] - vp0));
        CVT_PK(q3, __expf(vb1[2] - vp0), __expf(vb1[3] - vp0));
        union { unsigned w[4]; s16x8 v; } bu;
        bu.w[0] = q0; bu.w[1] = q1; bu.w[2] = q2; bu.w[3] = q3;
        Bf = bu.v;
    }
    const int tendo = SL * s + SL - 1;

    f32x4 pl0, pl1, pl2, pl3, qh0, qh1, qh2, qh3;
    LOADSLOT(pl0, qh0, t0)     LOADSLOT(pl1, qh1, t0 + 1)
    LOADSLOT(pl2, qh2, t0 + 2) LOADSLOT(pl3, qh3, t0 + 3)

    const f32x4 zz4 = {0.f, 0.f, 0.f, 0.f};
    float sU = s0, sC = s0, aQ = s0;
    float* op0 = out + ((size_t)t0 * CRF_B + b) * CRF_C + 4 * h;
    int t = t0;

#define STEP(PL_, PH_)                                                         \
    {                                                                          \
        f32x4 xl = PL_, xh = PH_;                                              \
        { int tn_ = t + 4; if (tn_ > tendo) tn_ = tendo;                       \
          LOADSLOT(PL_, PH_, tn_) }                                            \
        f32x4 D0 = __builtin_amdgcn_mfma_f32_16x16x32_bf16(A0, Bf, zz4, 0, 0, 0); \
        f32x4 D1 = __builtin_amdgcn_mfma_f32_16x16x32_bf16(A1, Bf, zz4, 0, 0, 0); \
        float dlt = sU - sC;                                                   \
        float f0 = __expf(xl[0] + dlt), f1 = __expf(xl[1] + dlt);              \
        float f2 = __expf(xl[2] + dlt), f3 = __expf(xl[3] + dlt);              \
        float g0 = __expf(xh[0] + dlt), g1 = __expf(xh[1] + dlt);              \
        float g2 = __expf(xh[2] + dlt), g3 = __expf(xh[3] + dlt);              \
        f32x4 alo, ahi;                                                        \
        alo[0] = xl[0] + sU + __logf(D0[0]);                                   \
        alo[1] = xl[1] + sU + __logf(D0[1]);                                   \
        alo[2] = xl[2] + sU + __logf(D0[2]);                                   \
        alo[3] = xl[3] + sU + __logf(D0[3]);                                   \
        ahi[0] = xh[0] + sU + __logf(D1[0]);                                   \
        ahi[1] = xh[1] + sU + __logf(D1[1]);                                   \
        ahi[2] = xh[2] + sU + __logf(D1[2]);                                   \
        ahi[3] = xh[3] + sU + __logf(D1[3]);                                   \
        *(f32x4*)op0 = alo;                                                    \
        *(f32x4*)(op0 + 16) = ahi;                                             \
        op0 += (size_t)CRF_B * CRF_C;                                          \
        float a0new = __shfl(alo[0], r, 64);                                   \
        unsigned w0, w1, w2, w3;                                               \
        CVT_PK(w0, D0[0] * f0, D0[1] * f1);                                    \
        CVT_PK(w1, D0[2] * f2, D0[3] * f3);                                    \
        CVT_PK(w2, D1[0] * g0, D1[1] * g1);                                    \
        CVT_PK(w3, D1[2] * g2, D1[3] * g3);                                    \
        SWAP32(w0, w2); SWAP16(w0, w2);                                        \
        SWAP32(w1, w3); SWAP16(w1, w3);                                        \
        {                                                                      \
            union { unsigned w[4]; s16x8 v; } bu_;                             \
            bu_.w[0] = w0; bu_.w[1] = w1; bu_.w[2] = w2; bu_.w[3] = w3;        \
            Bf = bu_.v;                                                        \
        }                                                                      \
        sU = sC; sC = aQ; aQ = a0new;                                          \
        ++t;                                                                   \
    }

    const int ngr = nst >> 2;
    for (int g = 0; g < ngr; ++g) {
        STEP(pl0, qh0) STEP(pl1, qh1) STEP(pl2, qh2) STEP(pl3, qh3)
    }
    if (nst & 3) {
        STEP(pl0, qh0) STEP(pl1, qh1) STEP(pl2, qh2)
    }
#undef STEP
}

__global__ __launch_bounds__(64) void crf_fwd_fallback(
    const float* __restrict__ x, const float* __restrict__ trans,
    const float* __restrict__ orig, float* __restrict__ out)
{
    const int l = threadIdx.x;
    const int r = l & 15;
    const int h = l >> 4;
    const int b = blockIdx.x * 16 + r;

    MAKE_AFRAGS();

    const float* xb = x + (size_t)b * CRF_T * CRF_C;
    float s0 = xb[0] + orig[0];

    f32x4 ib0 = *(const f32x4*)(xb + 8 * h);
    f32x4 ib1 = *(const f32x4*)(xb + 8 * h + 4);
    f32x4 ob0 = *(const f32x4*)(orig + 8 * h);
    f32x4 ob1 = *(const f32x4*)(orig + 8 * h + 4);
    unsigned q0, q1, q2, q3;
    CVT_PK(q0, __expf(ib0[0] + ob0[0] - s0), __expf(ib0[1] + ob0[1] - s0));
    CVT_PK(q1, __expf(ib0[2] + ob0[2] - s0), __expf(ib0[3] + ob0[3] - s0));
    CVT_PK(q2, __expf(ib1[0] + ob1[0] - s0), __expf(ib1[1] + ob1[1] - s0));
    CVT_PK(q3, __expf(ib1[2] + ob1[2] - s0), __expf(ib1[3] + ob1[3] - s0));
    s16x8 Bf;
    {
        union { unsigned w[4]; s16x8 v; } bu;
        bu.w[0] = q0; bu.w[1] = q1; bu.w[2] = q2; bu.w[3] = q3;
        Bf = bu.v;
    }
    {
        f32x4 xd0 = *(const f32x4*)(xb + 4 * h);
        f32x4 xd1 = *(const f32x4*)(xb + 16 + 4 * h);
        f32x4 od0 = *(const f32x4*)(orig + 4 * h);
        f32x4 od1 = *(const f32x4*)(orig + 16 + 4 * h);
        f32x4 a00, a01;
        #pragma unroll
        for (int i = 0; i < 4; ++i) { a00[i] = xd0[i] + od0[i]; a01[i] = xd1[i] + od1[i]; }
        *(f32x4*)(out + (size_t)b * CRF_C + 4 * h) = a00;
        *(f32x4*)(out + (size_t)b * CRF_C + 16 + 4 * h) = a01;
    }

    f32x4 pl0, pl1, pl2, pl3, qh0, qh1, qh2, qh3;
    LOADSLOT(pl0, qh0, 1) LOADSLOT(pl1, qh1, 2)
    LOADSLOT(pl2, qh2, 3) LOADSLOT(pl3, qh3, 4)

    const f32x4 zz4 = {0.f, 0.f, 0.f, 0.f};
    float sU = s0, sC = s0, aQ = s0;
    float* op0 = out + ((size_t)CRF_B + b) * CRF_C + 4 * h;
    int t = 1;

#define STEP(PL_, PH_)                                                         \
    {                                                                          \
        f32x4 xl = PL_, xh = PH_;                                              \
        { int tn_ = t + 4; if (tn_ > CRF_T - 1) tn_ = CRF_T - 1;               \
          LOADSLOT(PL_, PH_, tn_) }                                            \
        f32x4 D0 = __builtin_amdgcn_mfma_f32_16x16x32_bf16(A0, Bf, zz4, 0, 0, 0); \
        f32x4 D1 = __builtin_amdgcn_mfma_f32_16x16x32_bf16(A1, Bf, zz4, 0, 0, 0); \
        float dlt = sU - sC;                                                   \
        float f0 = __expf(xl[0] + dlt), f1 = __expf(xl[1] + dlt);              \
        float f2 = __expf(xl[2] + dlt), f3 = __expf(xl[3] + dlt);              \
        float g0 = __expf(xh[0] + dlt), g1 = __expf(xh[1] + dlt);              \
        float g2 = __expf(xh[2] + dlt), g3 = __expf(xh[3] + dlt);              \
        f32x4 alo, ahi;                                                        \
        alo[0] = xl[0] + sU + __logf(D0[0]);                                   \
        alo[1] = xl[1] + sU + __logf(D0[1]);                                   \
        alo[2] = xl[2] + sU + __logf(D0[2]);                                   \
        alo[3] = xl[3] + sU + __logf(D0[3]);                                   \
        ahi[0] = xh[0] + sU + __logf(D1[0]);                                   \
        ahi[1] = xh[1] + sU + __logf(D1[1]);                                   \
        ahi[2] = xh[2] + sU + __logf(D1[2]);                                   \
        ahi[3] = xh[3] + sU + __logf(D1[3]);                                   \
        *(f32x4*)op0 = alo;                                                    \
        *(f32x4*)(op0 + 16) = ahi;                                             \
        op0 += (size_t)CRF_B * CRF_C;                                          \
        float a0new = __shfl(alo[0], r, 64);                                   \
        unsigned w0, w1, w2, w3;                                               \
        CVT_PK(w0, D0[0] * f0, D0[1] * f1);                                    \
        CVT_PK(w1, D0[2] * f2, D0[3] * f3);                                    \
        CVT_PK(w2, D1[0] * g0, D1[1] * g1);                                    \
        CVT_PK(w3, D1[2] * g2, D1[3] * g3);                                    \
        SWAP32(w0, w2); SWAP16(w0, w2);                                        \
        SWAP32(w1, w3); SWAP16(w1, w3);                                        \
        {                                                                      \
            union { unsigned w[4]; s16x8 v; } bu_;                             \
            bu_.w[0] = w0; bu_.w[1] = w1; bu_.w[2] = w2; bu_.w[3] = w3;        \
            Bf = bu_.v;                                                        \
        }                                                                      \
        sU = sC; sC = aQ; aQ = a0new;                                          \
        ++t;                                                                   \
    }

    for (int g = 0; g < 127; ++g) {
        STEP(pl0, qh0) STEP(pl1, qh1) STEP(pl2, qh2) STEP(pl3, qh3)
    }
    STEP(pl0, qh0) STEP(pl1, qh1) STEP(pl2, qh2)
#undef STEP
}

extern "C" void kernel_launch(void* const* d_in, const int* in_sizes, int n_in,
                              void* d_out, int out_size, void* d_ws, size_t ws_size,
                              hipStream_t stream) {
    const float* pad_x = (const float*)d_in[0];
    const float* trans = (const float*)d_in[1];
    const float* orig  = (const float*)d_in[2];
    float* out = (float*)d_out;

    // --- Preferred: fused cooperative kernel (gg only: 256 KB of ws) ---
    if (ws_size >= (size_t)FSEG * CRF_B * sizeof(float)) {
        float* gg = (float*)d_ws;
        void* args[] = { (void*)&pad_x, (void*)&trans, (void*)&orig,
                         (void*)&gg, (void*)&out };
        hipError_t e = hipLaunchCooperativeKernel(
            (const void*)crf_fused_kernel,
            dim3(CRF_B / 16, FSEG / 2), dim3(128), args, 0, stream);
        if (e == hipSuccess) return;
        (void)hipGetLastError();   // clear sticky error; fall back
    }

    // --- Fallback: round-13 validated 2-kernel path ---
    auto need = [](int SL) {
        return (size_t)CRF_B * (CRF_T / SL) * (CRF_C + 1) * sizeof(float);
    };

    if (ws_size >= need(8)) {
        const int SEG_S = CRF_T / 8;
        float* snap = (float*)d_ws;
        float* gg   = snap + (size_t)CRF_B * SEG_S * CRF_C;
        crf_seam_kernel<8><<<dim3(CRF_B / 16, SEG_S), dim3(64), 0, stream>>>(
            pad_x, trans, orig, snap, gg);
        crf_out_kernel<8><<<dim3(CRF_B / 16, SEG_S), dim3(64), 0, stream>>>(
            pad_x, trans, orig, snap, gg, out);
    } else if (ws_size >= need(16)) {
        const int SEG_S = CRF_T / 16;
        float* snap = (float*)d_ws;
        float* gg   = snap + (size_t)CRF_B * SEG_S * CRF_C;
        crf_seam_kernel<16><<<dim3(CRF_B / 16, SEG_S), dim3(64), 0, stream>>>(
            pad_x, trans, orig, snap, gg);
        crf_out_kernel<16><<<dim3(CRF_B / 16, SEG_S), dim3(64), 0, stream>>>(
            pad_x, trans, orig, snap, gg, out);
    } else {
        crf_fwd_fallback<<<dim3(CRF_B / 16), dim3(64), 0, stream>>>(
            pad_x, trans, orig, out);
    }
}

// Round 15
// 54.878 us; speedup vs baseline: 7.8603x; 7.8603x over previous
//
#include <hip/hip_runtime.h>
#include <hip/hip_bf16.h>

#define CRF_B 1024
#define CRF_T 512
#define CRF_C 32
#define WARM  4    // validated rounds 12/13 (absmax 16.0)

typedef float f32x4 __attribute__((ext_vector_type(4)));
typedef short s16x8 __attribute__((ext_vector_type(8)));

static __device__ __forceinline__ unsigned f2bf(float f) {
    union { float f; unsigned u; } v; v.f = f;
    return (v.u + 0x7FFFu + ((v.u >> 16) & 1u)) >> 16;
}

#define CVT_PK(dst, lo, hi) \
    asm("v_cvt_pk_bf16_f32 %0, %1, %2" : "=v"(dst) : "v"(lo), "v"(hi))
#define SWAP32(a, b) \
    asm("v_permlane32_swap_b32 %0, %1" : "+v"(a), "+v"(b))
#define SWAP16(a, b) \
    asm("v_permlane16_swap_b32 %0, %1" : "+v"(a), "+v"(b))

#define MAKE_AFRAGS()                                                          \
    s16x8 A0, A1;                                                              \
    _Pragma("unroll")                                                          \
    for (int e = 0; e < 8; ++e) {                                              \
        int k_ = h * 8 + e;                                                    \
        A0[e] = (short)f2bf(__expf(trans[r * CRF_C + k_]));                    \
        A1[e] = (short)f2bf(__expf(trans[(16 + r) * CRF_C + k_]));             \
    }

#define LOADSLOT(PL_, PH_, TT_)                                                \
    { const float* pa_ = xb + (size_t)(TT_) * CRF_C;                           \
      PL_ = *(const f32x4*)(pa_ + 4 * h);                                      \
      PH_ = *(const f32x4*)(pa_ + 16 + 4 * h); }

// ============================================================================
// K1 (seam, SL=8, dual snapshots): segment s walks t_a+1..t_a+nsteps
// (s=0 exact from 0, 7 steps; s>0 flat-init at 8s-4, 11 steps).
// Snapshots (f32 log-space, wave-uniform in-loop stores — validated pattern):
//   k==3: snap[zz] for zz = (s==0 ? 1 : 2s)   (t = 3 or 8s-1)
//   k==7 (s>0): snap[2s+1]                     (t = 8s+3)
// v0save = k==3 value[0] (s>0 only; register).  After loop (h==0):
//   gg[s][b] = uval - v0save,  uval = value[0] at k==nsteps (t = 8(s+1)-1).
// ============================================================================
__global__ __launch_bounds__(64) void crf_seam8_kernel(
    const float* __restrict__ x, const float* __restrict__ trans,
    const float* __restrict__ orig, float* __restrict__ snap,
    float* __restrict__ gg)
{
    const int l = threadIdx.x;
    const int r = l & 15;
    const int h = l >> 4;
    const int b = blockIdx.x * 16 + r;
    const int s = blockIdx.y;          // 0..63

    MAKE_AFRAGS();

    const float* xb = x + (size_t)b * CRF_T * CRF_C;
    const int t_a    = (s == 0) ? 0 : (8 * s - WARM);
    const int nsteps = (s == 0) ? 7 : (8 + WARM - 1);   // 7 or 11
    const int tend   = t_a + nsteps;

    float base0;
    f32x4 ab0, ab1;
    {
        const float* row = xb + (size_t)t_a * CRF_C;
        ab0 = *(const f32x4*)(row + 8 * h);
        ab1 = *(const f32x4*)(row + 8 * h + 4);
        if (s == 0) {
            f32x4 ob0 = *(const f32x4*)(orig + 8 * h);
            f32x4 ob1 = *(const f32x4*)(orig + 8 * h + 4);
            #pragma unroll
            for (int i = 0; i < 4; ++i) { ab0[i] += ob0[i]; ab1[i] += ob1[i]; }
            base0 = row[0] + orig[0];
        } else {
            base0 = row[0];
        }
    }
    float A = base0;
    s16x8 Bf;
    {
        unsigned q0, q1, q2, q3;
        CVT_PK(q0, __expf(ab0[0] - base0), __expf(ab0[1] - base0));
        CVT_PK(q1, __expf(ab0[2] - base0), __expf(ab0[3] - base0));
        CVT_PK(q2, __expf(ab1[0] - base0), __expf(ab1[1] - base0));
        CVT_PK(q3, __expf(ab1[2] - base0), __expf(ab1[3] - base0));
        union { unsigned w[4]; s16x8 v; } bu;
        bu.w[0] = q0; bu.w[1] = q1; bu.w[2] = q2; bu.w[3] = q3;
        Bf = bu.v;
    }

    f32x4 pl0, pl1, pl2, pl3, qh0, qh1, qh2, qh3;
    LOADSLOT(pl0, qh0, t_a + 1) LOADSLOT(pl1, qh1, t_a + 2)
    LOADSLOT(pl2, qh2, t_a + 3) LOADSLOT(pl3, qh3, t_a + 4)

    const f32x4 zz4 = {0.f, 0.f, 0.f, 0.f};
    int t = t_a + 1, k = 1;
    float uval = 0.0f;
    float v0save = 0.0f;
    float* vrowA = snap + ((size_t)b * 128 + ((s == 0) ? 1 : (2 * s))) * CRF_C;
    float* vrowB = snap + ((size_t)b * 128 + (2 * s + 1)) * CRF_C;

#define PSTEP(PL_, PH_)                                                        \
    {                                                                          \
        f32x4 xl = PL_, xh = PH_;                                              \
        { int tn_ = t + 4; if (tn_ > tend) tn_ = tend;                         \
          LOADSLOT(PL_, PH_, tn_) }                                            \
        f32x4 D0 = __builtin_amdgcn_mfma_f32_16x16x32_bf16(A0, Bf, zz4, 0, 0, 0); \
        f32x4 D1 = __builtin_amdgcn_mfma_f32_16x16x32_bf16(A1, Bf, zz4, 0, 0, 0); \
        int ex = (int)((__float_as_uint(D0[0]) >> 23) & 0xFFu) - 127;          \
        ex = __shfl(ex, r, 64);                                                \
        float me = (float)ex;                                                  \
        float Aent = A;                                                        \
        A = Aent + me * 0.69314718055994530942f;                               \
        float f0 = exp2f(fmaf(xl[0], 1.44269504088896f, -me));                 \
        float f1 = exp2f(fmaf(xl[1], 1.44269504088896f, -me));                 \
        float f2 = exp2f(fmaf(xl[2], 1.44269504088896f, -me));                 \
        float f3 = exp2f(fmaf(xl[3], 1.44269504088896f, -me));                 \
        float g0 = exp2f(fmaf(xh[0], 1.44269504088896f, -me));                 \
        float g1 = exp2f(fmaf(xh[1], 1.44269504088896f, -me));                 \
        float g2 = exp2f(fmaf(xh[2], 1.44269504088896f, -me));                 \
        float g3 = exp2f(fmaf(xh[3], 1.44269504088896f, -me));                 \
        if (k == 3) {                        /* wave-uniform snapshot A */     \
            f32x4 vlo, vhi;                                                    \
            vlo[0] = xl[0] + Aent + __logf(D0[0]);                             \
            vlo[1] = xl[1] + Aent + __logf(D0[1]);                             \
            vlo[2] = xl[2] + Aent + __logf(D0[2]);                             \
            vlo[3] = xl[3] + Aent + __logf(D0[3]);                             \
            vhi[0] = xh[0] + Aent + __logf(D1[0]);                             \
            vhi[1] = xh[1] + Aent + __logf(D1[1]);                             \
            vhi[2] = xh[2] + Aent + __logf(D1[2]);                             \
            vhi[3] = xh[3] + Aent + __logf(D1[3]);                             \
            *(f32x4*)(vrowA + 4 * h) = vlo;                                    \
            *(f32x4*)(vrowA + 16 + 4 * h) = vhi;                               \
            if (s != 0) v0save = vlo[0];                                       \
        }                                                                      \
        if ((s != 0) && (k == 7)) {          /* wave-uniform snapshot B */     \
            f32x4 vlo, vhi;                                                    \
            vlo[0] = xl[0] + Aent + __logf(D0[0]);                             \
            vlo[1] = xl[1] + Aent + __logf(D0[1]);                             \
            vlo[2] = xl[2] + Aent + __logf(D0[2]);                             \
            vlo[3] = xl[3] + Aent + __logf(D0[3]);                             \
            vhi[0] = xh[0] + Aent + __logf(D1[0]);                             \
            vhi[1] = xh[1] + Aent + __logf(D1[1]);                             \
            vhi[2] = xh[2] + Aent + __logf(D1[2]);                             \
            vhi[3] = xh[3] + Aent + __logf(D1[3]);                             \
            *(f32x4*)(vrowB + 4 * h) = vlo;                                    \
            *(f32x4*)(vrowB + 16 + 4 * h) = vhi;                               \
        }                                                                      \
        if (k == nsteps) uval = xl[0] + Aent + __logf(D0[0]);                  \
        unsigned w0, w1, w2, w3;                                               \
        CVT_PK(w0, D0[0] * f0, D0[1] * f1);                                    \
        CVT_PK(w1, D0[2] * f2, D0[3] * f3);                                    \
        CVT_PK(w2, D1[0] * g0, D1[1] * g1);                                    \
        CVT_PK(w3, D1[2] * g2, D1[3] * g3);                                    \
        SWAP32(w0, w2); SWAP16(w0, w2);                                        \
        SWAP32(w1, w3); SWAP16(w1, w3);                                        \
        {                                                                      \
            union { unsigned w[4]; s16x8 v; } bu_;                             \
            bu_.w[0] = w0; bu_.w[1] = w1; bu_.w[2] = w2; bu_.w[3] = w3;        \
            Bf = bu_.v;                                                        \
        }                                                                      \
        ++t; ++k;                                                              \
    }

    const int ngr = nsteps >> 2;    // 7 or 11, both == 3 (mod 4)
    for (int g = 0; g < ngr; ++g) {
        PSTEP(pl0, qh0) PSTEP(pl1, qh1) PSTEP(pl2, qh2) PSTEP(pl3, qh3)
    }
    PSTEP(pl0, qh0) PSTEP(pl1, qh1) PSTEP(pl2, qh2)
#undef PSTEP

    if (h == 0) gg[(size_t)s * CRF_B + b] = uval - v0save;
}

// ============================================================================
// K2 (out, CPL=4): block zz writes rows [4zz, 4zz+4) (zz=0: t=0 exact + 3).
// zz>0: s8 = zz>>1; base = sum_{sp<s8} gg[sp][b] (coalesced, 4-way).
//   even zz: s0 = base                (= v0_{s8} + c_{s8}, round-11 identity)
//   odd  zz: s0 = base + vp[0] - v0prev, v0prev = (zz==1)?0:snap[zz-1][0]
//   state p = exp(vp[j] - vp[0]) from snap[zz]. 4-step chains, 8 waves/SIMD.
// ============================================================================
__global__ __launch_bounds__(64) void crf_out4_kernel(
    const float* __restrict__ x, const float* __restrict__ trans,
    const float* __restrict__ orig, const float* __restrict__ snap,
    const float* __restrict__ gg, float* __restrict__ out)
{
    const int l = threadIdx.x;
    const int r = l & 15;
    const int h = l >> 4;
    const int b = blockIdx.x * 16 + r;
    const int zz = blockIdx.y;         // 0..127

    MAKE_AFRAGS();

    const float* xb = x + (size_t)b * CRF_T * CRF_C;

    int t0, nst;
    float s0;
    s16x8 Bf;
    if (zz == 0) {
        t0 = 1; nst = 3;
        s0 = xb[0] + orig[0];
        f32x4 ib0 = *(const f32x4*)(xb + 8 * h);
        f32x4 ib1 = *(const f32x4*)(xb + 8 * h + 4);
        f32x4 ob0 = *(const f32x4*)(orig + 8 * h);
        f32x4 ob1 = *(const f32x4*)(orig + 8 * h + 4);
        unsigned q0, q1, q2, q3;
        CVT_PK(q0, __expf(ib0[0] + ob0[0] - s0), __expf(ib0[1] + ob0[1] - s0));
        CVT_PK(q1, __expf(ib0[2] + ob0[2] - s0), __expf(ib0[3] + ob0[3] - s0));
        CVT_PK(q2, __expf(ib1[0] + ob1[0] - s0), __expf(ib1[1] + ob1[1] - s0));
        CVT_PK(q3, __expf(ib1[2] + ob1[2] - s0), __expf(ib1[3] + ob1[3] - s0));
        union { unsigned w[4]; s16x8 v; } bu;
        bu.w[0] = q0; bu.w[1] = q1; bu.w[2] = q2; bu.w[3] = q3;
        Bf = bu.v;
        // t = 0 outputs (D-layout)
        f32x4 xd0 = *(const f32x4*)(xb + 4 * h);
        f32x4 xd1 = *(const f32x4*)(xb + 16 + 4 * h);
        f32x4 od0 = *(const f32x4*)(orig + 4 * h);
        f32x4 od1 = *(const f32x4*)(orig + 16 + 4 * h);
        f32x4 a00, a01;
        #pragma unroll
        for (int i = 0; i < 4; ++i) { a00[i] = xd0[i] + od0[i]; a01[i] = xd1[i] + od1[i]; }
        *(f32x4*)(out + (size_t)b * CRF_C + 4 * h) = a00;
        *(f32x4*)(out + (size_t)b * CRF_C + 16 + 4 * h) = a01;
    } else {
        t0 = 4 * zz; nst = 4;
        const int s8 = zz >> 1;
        const float* gb = gg + b;
        float c0 = 0.f, c1 = 0.f, c2 = 0.f, c3 = 0.f;
        int sp = 0;
        for (; sp + 4 <= s8; sp += 4) {
            c0 += gb[(size_t)(sp)     * CRF_B];
            c1 += gb[(size_t)(sp + 1) * CRF_B];
            c2 += gb[(size_t)(sp + 2) * CRF_B];
            c3 += gb[(size_t)(sp + 3) * CRF_B];
        }
        for (; sp < s8; ++sp) c0 += gb[(size_t)sp * CRF_B];
        float base = (c0 + c1) + (c2 + c3);

        const float* vp = snap + ((size_t)b * 128 + zz) * CRF_C;
        const float vp0 = vp[0];
        if (zz & 1) {
            float v0prev = (zz == 1) ? 0.0f
                         : snap[((size_t)b * 128 + zz - 1) * CRF_C];
            s0 = base + vp0 - v0prev;
        } else {
            s0 = base;
        }
        f32x4 vb0 = *(const f32x4*)(vp + 8 * h);
        f32x4 vb1 = *(const f32x4*)(vp + 8 * h + 4);
        unsigned q0, q1, q2, q3;
        CVT_PK(q0, __expf(vb0[0] - vp0), __expf(vb0[1] - vp0));
        CVT_PK(q1, __expf(vb0[2] - vp0), __expf(vb0[3] - vp0));
        CVT_PK(q2, __expf(vb1[0] - vp0), __expf(vb1[1] - vp0));
        CVT_PK(q3, __expf(vb1[2] - vp0), __expf(vb1[3] - vp0));
        union { unsigned w[4]; s16x8 v; } bu;
        bu.w[0] = q0; bu.w[1] = q1; bu.w[2] = q2; bu.w[3] = q3;
        Bf = bu.v;
    }
    const int tendo = (zz == 0) ? 3 : (4 * zz + 3);

    f32x4 pl0, pl1, pl2, pl3, qh0, qh1, qh2, qh3;
    LOADSLOT(pl0, qh0, t0)     LOADSLOT(pl1, qh1, t0 + 1)
    LOADSLOT(pl2, qh2, t0 + 2) LOADSLOT(pl3, qh3, t0 + 3)

    const f32x4 zz4 = {0.f, 0.f, 0.f, 0.f};
    float sU = s0, sC = s0, aQ = s0;
    float* op0 = out + ((size_t)t0 * CRF_B + b) * CRF_C + 4 * h;
    int t = t0;

#define STEP(PL_, PH_)                                                         \
    {                                                                          \
        f32x4 xl = PL_, xh = PH_;                                              \
        { int tn_ = t + 4; if (tn_ > tendo) tn_ = tendo;                       \
          LOADSLOT(PL_, PH_, tn_) }                                            \
        f32x4 D0 = __builtin_amdgcn_mfma_f32_16x16x32_bf16(A0, Bf, zz4, 0, 0, 0); \
        f32x4 D1 = __builtin_amdgcn_mfma_f32_16x16x32_bf16(A1, Bf, zz4, 0, 0, 0); \
        float dlt = sU - sC;                                                   \
        float f0 = __expf(xl[0] + dlt), f1 = __expf(xl[1] + dlt);              \
        float f2 = __expf(xl[2] + dlt), f3 = __expf(xl[3] + dlt);              \
        float g0 = __expf(xh[0] + dlt), g1 = __expf(xh[1] + dlt);              \
        float g2 = __expf(xh[2] + dlt), g3 = __expf(xh[3] + dlt);              \
        f32x4 alo, ahi;                                                        \
        alo[0] = xl[0] + sU + __logf(D0[0]);                                   \
        alo[1] = xl[1] + sU + __logf(D0[1]);                                   \
        alo[2] = xl[2] + sU + __logf(D0[2]);                                   \
        alo[3] = xl[3] + sU + __logf(D0[3]);                                   \
        ahi[0] = xh[0] + sU + __logf(D1[0]);                                   \
        ahi[1] = xh[1] + sU + __logf(D1[1]);                                   \
        ahi[2] = xh[2] + sU + __logf(D1[2]);                                   \
        ahi[3] = xh[3] + sU + __logf(D1[3]);                                   \
        *(f32x4*)op0 = alo;                                                    \
        *(f32x4*)(op0 + 16) = ahi;                                             \
        op0 += (size_t)CRF_B * CRF_C;                                          \
        float a0new = __shfl(alo[0], r, 64);                                   \
        unsigned w0, w1, w2, w3;                                               \
        CVT_PK(w0, D0[0] * f0, D0[1] * f1);                                    \
        CVT_PK(w1, D0[2] * f2, D0[3] * f3);                                    \
        CVT_PK(w2, D1[0] * g0, D1[1] * g1);                                    \
        CVT_PK(w3, D1[2] * g2, D1[3] * g3);                                    \
        SWAP32(w0, w2); SWAP16(w0, w2);                                        \
        SWAP32(w1, w3); SWAP16(w1, w3);                                        \
        {                                                                      \
            union { unsigned w[4]; s16x8 v; } bu_;                             \
            bu_.w[0] = w0; bu_.w[1] = w1; bu_.w[2] = w2; bu_.w[3] = w3;        \
            Bf = bu_.v;                                                        \
        }                                                                      \
        sU = sC; sC = aQ; aQ = a0new;                                          \
        ++t;                                                                   \
    }

    const int ngr = nst >> 2;
    for (int g = 0; g < ngr; ++g) {
        STEP(pl0, qh0) STEP(pl1, qh1) STEP(pl2, qh2) STEP(pl3, qh3)
    }
    if (nst & 3) {    // tail is 0 or 3
        STEP(pl0, qh0) STEP(pl1, qh1) STEP(pl2, qh2)
    }
#undef STEP
}

// ============================================================================
// Round-13 validated 2-kernel path (tier-2) + round-5 fallback (tier-3)
// ============================================================================
template <int SL>
__global__ __launch_bounds__(64) void crf_seam_kernel(
    const float* __restrict__ x, const float* __restrict__ trans,
    const float* __restrict__ orig, float* __restrict__ snap,
    float* __restrict__ gg)
{
    const int SEG_S = CRF_T / SL;
    const int l = threadIdx.x;
    const int r = l & 15;
    const int h = l >> 4;
    const int b = blockIdx.x * 16 + r;
    const int s = blockIdx.y;

    MAKE_AFRAGS();

    const float* xb = x + (size_t)b * CRF_T * CRF_C;
    const int t_a    = (s == 0) ? 0 : (SL * s - WARM);
    const int nsteps = (s == 0) ? (SL - 1) : (SL + WARM - 1);
    const int tend   = t_a + nsteps;

    float base0;
    f32x4 ab0, ab1;
    {
        const float* row = xb + (size_t)t_a * CRF_C;
        ab0 = *(const f32x4*)(row + 8 * h);
        ab1 = *(const f32x4*)(row + 8 * h + 4);
        if (s == 0) {
            f32x4 ob0 = *(const f32x4*)(orig + 8 * h);
            f32x4 ob1 = *(const f32x4*)(orig + 8 * h + 4);
            #pragma unroll
            for (int i = 0; i < 4; ++i) { ab0[i] += ob0[i]; ab1[i] += ob1[i]; }
            base0 = row[0] + orig[0];
        } else {
            base0 = row[0];
        }
    }
    float A = base0;
    s16x8 Bf;
    {
        unsigned q0, q1, q2, q3;
        CVT_PK(q0, __expf(ab0[0] - base0), __expf(ab0[1] - base0));
        CVT_PK(q1, __expf(ab0[2] - base0), __expf(ab0[3] - base0));
        CVT_PK(q2, __expf(ab1[0] - base0), __expf(ab1[1] - base0));
        CVT_PK(q3, __expf(ab1[2] - base0), __expf(ab1[3] - base0));
        union { unsigned w[4]; s16x8 v; } bu;
        bu.w[0] = q0; bu.w[1] = q1; bu.w[2] = q2; bu.w[3] = q3;
        Bf = bu.v;
    }

    f32x4 pl0, pl1, pl2, pl3, qh0, qh1, qh2, qh3;
    LOADSLOT(pl0, qh0, t_a + 1) LOADSLOT(pl1, qh1, t_a + 2)
    LOADSLOT(pl2, qh2, t_a + 3) LOADSLOT(pl3, qh3, t_a + 4)

    const f32x4 zz4 = {0.f, 0.f, 0.f, 0.f};
    int t = t_a + 1, k = 1;
    float uval = 0.0f;
    float v0save = 0.0f;
    float* vrow = snap + ((size_t)b * SEG_S + s) * CRF_C;

#define PSTEP(PL_, PH_)                                                        \
    {                                                                          \
        f32x4 xl = PL_, xh = PH_;                                              \
        { int tn_ = t + 4; if (tn_ > tend) tn_ = tend;                         \
          LOADSLOT(PL_, PH_, tn_) }                                            \
        f32x4 D0 = __builtin_amdgcn_mfma_f32_16x16x32_bf16(A0, Bf, zz4, 0, 0, 0); \
        f32x4 D1 = __builtin_amdgcn_mfma_f32_16x16x32_bf16(A1, Bf, zz4, 0, 0, 0); \
        int ex = (int)((__float_as_uint(D0[0]) >> 23) & 0xFFu) - 127;          \
        ex = __shfl(ex, r, 64);                                                \
        float me = (float)ex;                                                  \
        float Aent = A;                                                        \
        A = Aent + me * 0.69314718055994530942f;                               \
        float f0 = exp2f(fmaf(xl[0], 1.44269504088896f, -me));                 \
        float f1 = exp2f(fmaf(xl[1], 1.44269504088896f, -me));                 \
        float f2 = exp2f(fmaf(xl[2], 1.44269504088896f, -me));                 \
        float f3 = exp2f(fmaf(xl[3], 1.44269504088896f, -me));                 \
        float g0 = exp2f(fmaf(xh[0], 1.44269504088896f, -me));                 \
        float g1 = exp2f(fmaf(xh[1], 1.44269504088896f, -me));                 \
        float g2 = exp2f(fmaf(xh[2], 1.44269504088896f, -me));                 \
        float g3 = exp2f(fmaf(xh[3], 1.44269504088896f, -me));                 \
        if ((s != 0) && (k == WARM - 1)) {                                     \
            f32x4 vlo, vhi;                                                    \
            vlo[0] = xl[0] + Aent + __logf(D0[0]);                             \
            vlo[1] = xl[1] + Aent + __logf(D0[1]);                             \
            vlo[2] = xl[2] + Aent + __logf(D0[2]);                             \
            vlo[3] = xl[3] + Aent + __logf(D0[3]);                             \
            vhi[0] = xh[0] + Aent + __logf(D1[0]);                             \
            vhi[1] = xh[1] + Aent + __logf(D1[1]);                             \
            vhi[2] = xh[2] + Aent + __logf(D1[2]);                             \
            vhi[3] = xh[3] + Aent + __logf(D1[3]);                             \
            *(f32x4*)(vrow + 4 * h) = vlo;                                     \
            *(f32x4*)(vrow + 16 + 4 * h) = vhi;                                \
            v0save = vlo[0];                                                   \
        }                                                                      \
        if (k == nsteps) uval = xl[0] + Aent + __logf(D0[0]);                  \
        unsigned w0, w1, w2, w3;                                               \
        CVT_PK(w0, D0[0] * f0, D0[1] * f1);                                    \
        CVT_PK(w1, D0[2] * f2, D0[3] * f3);                                    \
        CVT_PK(w2, D1[0] * g0, D1[1] * g1);                                    \
        CVT_PK(w3, D1[2] * g2, D1[3] * g3);                                    \
        SWAP32(w0, w2); SWAP16(w0, w2);                                        \
        SWAP32(w1, w3); SWAP16(w1, w3);                                        \
        {                                                                      \
            union { unsigned w[4]; s16x8 v; } bu_;                             \
            bu_.w[0] = w0; bu_.w[1] = w1; bu_.w[2] = w2; bu_.w[3] = w3;        \
            Bf = bu_.v;                                                        \
        }                                                                      \
        ++t; ++k;                                                              \
    }

    const int ngr = nsteps >> 2;
    for (int g = 0; g < ngr; ++g) {
        PSTEP(pl0, qh0) PSTEP(pl1, qh1) PSTEP(pl2, qh2) PSTEP(pl3, qh3)
    }
    PSTEP(pl0, qh0) PSTEP(pl1, qh1) PSTEP(pl2, qh2)
#undef PSTEP

    if (h == 0) gg[(size_t)s * CRF_B + b] = uval - v0save;
}

template <int SL>
__global__ __launch_bounds__(64) void crf_out_kernel(
    const float* __restrict__ x, const float* __restrict__ trans,
    const float* __restrict__ orig, const float* __restrict__ snap,
    const float* __restrict__ gg, float* __restrict__ out)
{
    const int SEG_S = CRF_T / SL;
    const int l = threadIdx.x;
    const int r = l & 15;
    const int h = l >> 4;
    const int b = blockIdx.x * 16 + r;
    const int s = blockIdx.y;

    MAKE_AFRAGS();

    const float* xb = x + (size_t)b * CRF_T * CRF_C;

    int t0, nst;
    float s0;
    s16x8 Bf;
    if (s == 0) {
        t0 = 1; nst = SL - 1;
        s0 = xb[0] + orig[0];
        f32x4 ib0 = *(const f32x4*)(xb + 8 * h);
        f32x4 ib1 = *(const f32x4*)(xb + 8 * h + 4);
        f32x4 ob0 = *(const f32x4*)(orig + 8 * h);
        f32x4 ob1 = *(const f32x4*)(orig + 8 * h + 4);
        unsigned q0, q1, q2, q3;
        CVT_PK(q0, __expf(ib0[0] + ob0[0] - s0), __expf(ib0[1] + ob0[1] - s0));
        CVT_PK(q1, __expf(ib0[2] + ob0[2] - s0), __expf(ib0[3] + ob0[3] - s0));
        CVT_PK(q2, __expf(ib1[0] + ob1[0] - s0), __expf(ib1[1] + ob1[1] - s0));
        CVT_PK(q3, __expf(ib1[2] + ob1[2] - s0), __expf(ib1[3] + ob1[3] - s0));
        union { unsigned w[4]; s16x8 v; } bu;
        bu.w[0] = q0; bu.w[1] = q1; bu.w[2] = q2; bu.w[3] = q3;
        Bf = bu.v;
        f32x4 xd0 = *(const f32x4*)(xb + 4 * h);
        f32x4 xd1 = *(const f32x4*)(xb + 16 + 4 * h);
        f32x4 od0 = *(const f32x4*)(orig + 4 * h);
        f32x4 od1 = *(const f32x4*)(orig + 16 + 4 * h);
        f32x4 a00, a01;
        #pragma unroll
        for (int i = 0; i < 4; ++i) { a00[i] = xd0[i] + od0[i]; a01[i] = xd1[i] + od1[i]; }
        *(f32x4*)(out + (size_t)b * CRF_C + 4 * h) = a00;
        *(f32x4*)(out + (size_t)b * CRF_C + 16 + 4 * h) = a01;
    } else {
        t0 = SL * s; nst = SL;
        const float* gb = gg + b;
        float c0 = 0.f, c1 = 0.f, c2 = 0.f, c3 = 0.f;
        int sp = 0;
        for (; sp + 4 <= s; sp += 4) {
            c0 += gb[(size_t)(sp)     * CRF_B];
            c1 += gb[(size_t)(sp + 1) * CRF_B];
            c2 += gb[(size_t)(sp + 2) * CRF_B];
            c3 += gb[(size_t)(sp + 3) * CRF_B];
        }
        for (; sp < s; ++sp) c0 += gb[(size_t)sp * CRF_B];
        s0 = (c0 + c1) + (c2 + c3);

        const float* vp = snap + ((size_t)b * SEG_S + s) * CRF_C;
        const float vp0 = vp[0];
        f32x4 vb0 = *(const f32x4*)(vp + 8 * h);
        f32x4 vb1 = *(const f32x4*)(vp + 8 * h + 4);
        unsigned q0, q1, q2, q3;
        CVT_PK(q0, __expf(vb0[0] - vp0), __expf(vb0[1] - vp0));
        CVT_PK(q1, __expf(vb0[2] - vp0), __expf(vb0[3] - vp0));
        CVT_PK(q2, __expf(vb1[0] - vp0), __expf(vb1[1] - vp0));
        CVT_PK(q3, __expf(vb1[2] - vp0), __expf(vb1[3] - vp0));
        union { unsigned w[4]; s16x8 v; } bu;
        bu.w[0] = q0; bu.w[1] = q1; bu.w[2] = q2; bu.w[3] = q3;
        Bf = bu.v;
    }
    const int tendo = SL * s + SL - 1;

    f32x4 pl0, pl1, pl2, pl3, qh0, qh1, qh2, qh3;
    LOADSLOT(pl0, qh0, t0)     LOADSLOT(pl1, qh1, t0 + 1)
    LOADSLOT(pl2, qh2, t0 + 2) LOADSLOT(pl3, qh3, t0 + 3)

    const f32x4 zz4 = {0.f, 0.f, 0.f, 0.f};
    float sU = s0, sC = s0, aQ = s0;
    float* op0 = out + ((size_t)t0 * CRF_B + b) * CRF_C + 4 * h;
    int t = t0;

#define STEP(PL_, PH_)                                                         \
    {                                                                          \
        f32x4 xl = PL_, xh = PH_;                                              \
        { int tn_ = t + 4; if (tn_ > tendo) tn_ = tendo;                       \
          LOADSLOT(PL_, PH_, tn_) }                                            \
        f32x4 D0 = __builtin_amdgcn_mfma_f32_16x16x32_bf16(A0, Bf, zz4, 0, 0, 0); \
        f32x4 D1 = __builtin_amdgcn_mfma_f32_16x16x32_bf16(A1, Bf, zz4, 0, 0, 0); \
        float dlt = sU - sC;                                                   \
        float f0 = __expf(xl[0] + dlt), f1 = __expf(xl[1] + dlt);              \
        float f2 = __expf(xl[2] + dlt), f3 = __expf(xl[3] + dlt);              \
        float g0 = __expf(xh[0] + dlt), g1 = __expf(xh[1] + dlt);              \
        float g2 = __expf(xh[2] + dlt), g3 = __expf(xh[3] + dlt);              \
        f32x4 alo, ahi;                                                        \
        alo[0] = xl[0] + sU + __logf(D0[0]);                                   \
        alo[1] = xl[1] + sU + __logf(D0[1]);                                   \
        alo[2] = xl[2] + sU + __logf(D0[2]);                                   \
        alo[3] = xl[3] + sU + __logf(D0[3]);                                   \
        ahi[0] = xh[0] + sU + __logf(D1[0]);                                   \
        ahi[1] = xh[1] + sU + __logf(D1[1]);                                   \
        ahi[2] = xh[2] + sU + __logf(D1[2]);                                   \
        ahi[3] = xh[3] + sU + __logf(D1[3]);                                   \
        *(f32x4*)op0 = alo;                                                    \
        *(f32x4*)(op0 + 16) = ahi;                                             \
        op0 += (size_t)CRF_B * CRF_C;                                          \
        float a0new = __shfl(alo[0], r, 64);                                   \
        unsigned w0, w1, w2, w3;                                               \
        CVT_PK(w0, D0[0] * f0, D0[1] * f1);                                    \
        CVT_PK(w1, D0[2] * f2, D0[3] * f3);                                    \
        CVT_PK(w2, D1[0] * g0, D1[1] * g1);                                    \
        CVT_PK(w3, D1[2] * g2, D1[3] * g3);                                    \
        SWAP32(w0, w2); SWAP16(w0, w2);                                        \
        SWAP32(w1, w3); SWAP16(w1, w3);                                        \
        {                                                                      \
            union { unsigned w[4]; s16x8 v; } bu_;                             \
            bu_.w[0] = w0; bu_.w[1] = w1; bu_.w[2] = w2; bu_.w[3] = w3;        \
            Bf = bu_.v;                                                        \
        }                                                                      \
        sU = sC; sC = aQ; aQ = a0new;                                          \
        ++t;                                                                   \
    }

    const int ngr = nst >> 2;
    for (int g = 0; g < ngr; ++g) {
        STEP(pl0, qh0) STEP(pl1, qh1) STEP(pl2, qh2) STEP(pl3, qh3)
    }
    if (nst & 3) {
        STEP(pl0, qh0) STEP(pl1, qh1) STEP(pl2, qh2)
    }
#undef STEP
}

__global__ __launch_bounds__(64) void crf_fwd_fallback(
    const float* __restrict__ x, const float* __restrict__ trans,
    const float* __restrict__ orig, float* __restrict__ out)
{
    const int l = threadIdx.x;
    const int r = l & 15;
    const int h = l >> 4;
    const int b = blockIdx.x * 16 + r;

    MAKE_AFRAGS();

    const float* xb = x + (size_t)b * CRF_T * CRF_C;
    float s0 = xb[0] + orig[0];

    f32x4 ib0 = *(const f32x4*)(xb + 8 * h);
    f32x4 ib1 = *(const f32x4*)(xb + 8 * h + 4);
    f32x4 ob0 = *(const f32x4*)(orig + 8 * h);
    f32x4 ob1 = *(const f32x4*)(orig + 8 * h + 4);
    unsigned q0, q1, q2, q3;
    CVT_PK(q0, __expf(ib0[0] + ob0[0] - s0), __expf(ib0[1] + ob0[1] - s0));
    CVT_PK(q1, __expf(ib0[2] + ob0[2] - s0), __expf(ib0[3] + ob0[3] - s0));
    CVT_PK(q2, __expf(ib1[0] + ob1[0] - s0), __expf(ib1[1] + ob1[1] - s0));
    CVT_PK(q3, __expf(ib1[2] + ob1[2] - s0), __expf(ib1[3] + ob1[3] - s0));
    s16x8 Bf;
    {
        union { unsigned w[4]; s16x8 v; } bu;
        bu.w[0] = q0; bu.w[1] = q1; bu.w[2] = q2; bu.w[3] = q3;
        Bf = bu.v;
    }
    {
        f32x4 xd0 = *(const f32x4*)(xb + 4 * h);
        f32x4 xd1 = *(const f32x4*)(xb + 16 + 4 * h);
        f32x4 od0 = *(const f32x4*)(orig + 4 * h);
        f32x4 od1 = *(const f32x4*)(orig + 16 + 4 * h);
        f32x4 a00, a01;
        #pragma unroll
        for (int i = 0; i < 4; ++i) { a00[i] = xd0[i] + od0[i]; a01[i] = xd1[i] + od1[i]; }
        *(f32x4*)(out + (size_t)b * CRF_C + 4 * h) = a00;
        *(f32x4*)(out + (size_t)b * CRF_C + 16 + 4 * h) = a01;
    }

    f32x4 pl0, pl1, pl2, pl3, qh0, qh1, qh2, qh3;
    LOADSLOT(pl0, qh0, 1) LOADSLOT(pl1, qh1, 2)
    LOADSLOT(pl2, qh2, 3) LOADSLOT(pl3, qh3, 4)

    const f32x4 zz4 = {0.f, 0.f, 0.f, 0.f};
    float sU = s0, sC = s0, aQ = s0;
    float* op0 = out + ((size_t)CRF_B + b) * CRF_C + 4 * h;
    int t = 1;

#define STEP(PL_, PH_)                                                         \
    {                                                                          \
        f32x4 xl = PL_, xh = PH_;                                              \
        { int tn_ = t + 4; if (tn_ > CRF_T - 1) tn_ = CRF_T - 1;               \
          LOADSLOT(PL_, PH_, tn_) }                                            \
        f32x4 D0 = __builtin_amdgcn_mfma_f32_16x16x32_bf16(A0, Bf, zz4, 0, 0, 0); \
        f32x4 D1 = __builtin_amdgcn_mfma_f32_16x16x32_bf16(A1, Bf, zz4, 0, 0, 0); \
        float dlt = sU - sC;                                                   \
        float f0 = __expf(xl[0] + dlt), f1 = __expf(xl[1] + dlt);              \
        float f2 = __expf(xl[2] + dlt), f3 = __expf(xl[3] + dlt);              \
        float g0 = __expf(xh[0] + dlt), g1 = __expf(xh[1] + dlt);              \
        float g2 = __expf(xh[2] + dlt), g3 = __expf(xh[3] + dlt);              \
        f32x4 alo, ahi;                                                        \
        alo[0] = xl[0] + sU + __logf(D0[0]);                                   \
        alo[1] = xl[1] + sU + __logf(D0[1]);                                   \
        alo[2] = xl[2] + sU + __logf(D0[2]);                                   \
        alo[3] = xl[3] + sU + __logf(D0[3]);                                   \
        ahi[0] = xh[0] + sU + __logf(D1[0]);                                   \
        ahi[1] = xh[1] + sU + __logf(D1[1]);                                   \
        ahi[2] = xh[2] + sU + __logf(D1[2]);                                   \
        ahi[3] = xh[3] + sU + __logf(D1[3]);                                   \
        *(f32x4*)op0 = alo;                                                    \
        *(f32x4*)(op0 + 16) = ahi;                                             \
        op0 += (size_t)CRF_B * CRF_C;                                          \
        float a0new = __shfl(alo[0], r, 64);                                   \
        unsigned w0, w1, w2, w3;                                               \
        CVT_PK(w0, D0[0] * f0, D0[1] * f1);                                    \
        CVT_PK(w1, D0[2] * f2, D0[3] * f3);                                    \
        CVT_PK(w2, D1[0] * g0, D1[1] * g1);                                    \
        CVT_PK(w3, D1[2] * g2, D1[3] * g3);                                    \
        SWAP32(w0, w2); SWAP16(w0, w2);                                        \
        SWAP32(w1, w3); SWAP16(w1, w3);                                        \
        {                                                                      \
            union { unsigned w[4]; s16x8 v; } bu_;                             \
            bu_.w[0] = w0; bu_.w[1] = w1; bu_.w[2] = w2; bu_.w[3] = w3;        \
            Bf = bu_.v;                                                        \
        }                                                                      \
        sU = sC; sC = aQ; aQ = a0new;                                          \
        ++t;                                                                   \
    }

    for (int g = 0; g < 127; ++g) {
        STEP(pl0, qh0) STEP(pl1, qh1) STEP(pl2, qh2) STEP(pl3, qh3)
    }
    STEP(pl0, qh0) STEP(pl1, qh1) STEP(pl2, qh2)
#undef STEP
}

extern "C" void kernel_launch(void* const* d_in, const int* in_sizes, int n_in,
                              void* d_out, int out_size, void* d_ws, size_t ws_size,
                              hipStream_t stream) {
    const float* pad_x = (const float*)d_in[0];
    const float* trans = (const float*)d_in[1];
    const float* orig  = (const float*)d_in[2];
    float* out = (float*)d_out;

    // Tier 1: dual-snapshot path. snap[B][128][32] f32 (16 MB) + gg[64][B].
    const size_t need_new =
        (size_t)CRF_B * (128 * CRF_C + 64) * sizeof(float);   // ~17.04 MB
    // Tier 2/3 sizes (round-13 path)
    auto need = [](int SL) {
        return (size_t)CRF_B * (CRF_T / SL) * (CRF_C + 1) * sizeof(float);
    };

    if (ws_size >= need_new) {
        float* snap = (float*)d_ws;
        float* gg   = snap + (size_t)CRF_B * 128 * CRF_C;
        crf_seam8_kernel<<<dim3(CRF_B / 16, 64), dim3(64), 0, stream>>>(
            pad_x, trans, orig, snap, gg);
        crf_out4_kernel<<<dim3(CRF_B / 16, 128), dim3(64), 0, stream>>>(
            pad_x, trans, orig, snap, gg, out);
    } else if (ws_size >= need(8)) {
        const int SEG_S = CRF_T / 8;
        float* snap = (float*)d_ws;
        float* gg   = snap + (size_t)CRF_B * SEG_S * CRF_C;
        crf_seam_kernel<8><<<dim3(CRF_B / 16, SEG_S), dim3(64), 0, stream>>>(
            pad_x, trans, orig, snap, gg);
        crf_out_kernel<8><<<dim3(CRF_B / 16, SEG_S), dim3(64), 0, stream>>>(
            pad_x, trans, orig, snap, gg, out);
    } else if (ws_size >= need(16)) {
        const int SEG_S = CRF_T / 16;
        float* snap = (float*)d_ws;
        float* gg   = snap + (size_t)CRF_B * SEG_S * CRF_C;
        crf_seam_kernel<16><<<dim3(CRF_B / 16, SEG_S), dim3(64), 0, stream>>>(
            pad_x, trans, orig, snap, gg);
        crf_out_kernel<16><<<dim3(CRF_B / 16, SEG_S), dim3(64), 0, stream>>>(
            pad_x, trans, orig, snap, gg, out);
    } else {
        crf_fwd_fallback<<<dim3(CRF_B / 16), dim3(64), 0, stream>>>(
            pad_x, trans, orig, out);
    }
}

// Round 16
// 49.500 us; speedup vs baseline: 8.7145x; 1.1087x over previous
//
#include <hip/hip_runtime.h>
#include <hip/hip_bf16.h>

#define CRF_B 1024
#define CRF_T 512
#define CRF_C 32
#define WARM  4    // warmup steps before a checkpoint.
                   // Birkhoff: err <= 2*0.462^(WARM-1) ~ 0.20 log-space,
                   // invisible vs bf16 compare floor (16) and threshold (46).
                   // Validated numerically rounds 12/13 (absmax 16.0).
// DESIGN OPTIMUM (rounds 12/13/15): SL=8, WARM=4, 2 stream-ordered kernels.
//  - SL=4 (r12): -per-block fixed cost dominates -> 62us
//  - CPL=4 K2 (r15): same fixed-cost failure -> 54.9us
//  - cooperative fused (r14): grid.sync ~400us on 2048 blocks -> 431us
//  - this config (r13): 49.6us

typedef float f32x4 __attribute__((ext_vector_type(4)));
typedef short s16x8 __attribute__((ext_vector_type(8)));

// f32 -> bf16 bits, round-nearest-even (init/const path only)
static __device__ __forceinline__ unsigned f2bf(float f) {
    union { float f; unsigned u; } v; v.f = f;
    return (v.u + 0x7FFFu + ((v.u >> 16) & 1u)) >> 16;
}

#define CVT_PK(dst, lo, hi) \
    asm("v_cvt_pk_bf16_f32 %0, %1, %2" : "=v"(dst) : "v"(lo), "v"(hi))
#define SWAP32(a, b) \
    asm("v_permlane32_swap_b32 %0, %1" : "+v"(a), "+v"(b))
#define SWAP16(a, b) \
    asm("v_permlane16_swap_b32 %0, %1" : "+v"(a), "+v"(b))

#define MAKE_AFRAGS()                                                          \
    s16x8 A0, A1;                                                              \
    _Pragma("unroll")                                                          \
    for (int e = 0; e < 8; ++e) {                                              \
        int k_ = h * 8 + e;                                                    \
        A0[e] = (short)f2bf(__expf(trans[r * CRF_C + k_]));                    \
        A1[e] = (short)f2bf(__expf(trans[(16 + r) * CRF_C + k_]));             \
    }

#define LOADSLOT(PL_, PH_, TT_)                                                \
    { const float* pa_ = xb + (size_t)(TT_) * CRF_C;                           \
      PL_ = *(const f32x4*)(pa_ + 4 * h);                                      \
      PH_ = *(const f32x4*)(pa_ + 16 + 4 * h); }

// ============================================================================
// K1 (seam), SL = segment length, SEG_S = 512/SL segments.
// s=0: exact chain from t=0 (no checkpoint). s>0: flat-init at SL*s-WARM,
// checkpoint (f32 log-space alphas) at k=WARM-1 (t = SL*s-1) into
// snap[b][s][0..31]. v0save kept in-register (NO divergent store in-loop —
// rounds 8/10 NaN'd with lane-divergent stores inside the unrolled loop);
// after the loop h==0 stores gg[s][b] = uval - v0save (transposed).
// ============================================================================
template <int SL>
__global__ __launch_bounds__(64) void crf_seam_kernel(
    const float* __restrict__ x, const float* __restrict__ trans,
    const float* __restrict__ orig, float* __restrict__ snap,
    float* __restrict__ gg)
{
    const int SEG_S = CRF_T / SL;
    const int l = threadIdx.x;
    const int r = l & 15;
    const int h = l >> 4;
    const int b = blockIdx.x * 16 + r;
    const int s = blockIdx.y;

    MAKE_AFRAGS();

    const float* xb = x + (size_t)b * CRF_T * CRF_C;
    const int t_a    = (s == 0) ? 0 : (SL * s - WARM);
    const int nsteps = (s == 0) ? (SL - 1) : (SL + WARM - 1);
    const int tend   = t_a + nsteps;

    // init state at t_a
    float base0;
    f32x4 ab0, ab1;
    {
        const float* row = xb + (size_t)t_a * CRF_C;
        ab0 = *(const f32x4*)(row + 8 * h);
        ab1 = *(const f32x4*)(row + 8 * h + 4);
        if (s == 0) {
            f32x4 ob0 = *(const f32x4*)(orig + 8 * h);
            f32x4 ob1 = *(const f32x4*)(orig + 8 * h + 4);
            #pragma unroll
            for (int i = 0; i < 4; ++i) { ab0[i] += ob0[i]; ab1[i] += ob1[i]; }
            base0 = row[0] + orig[0];
        } else {
            base0 = row[0];
        }
    }
    float A = base0;   // spec alpha ~= log(p) + A
    s16x8 Bf;
    {
        unsigned q0, q1, q2, q3;
        CVT_PK(q0, __expf(ab0[0] - base0), __expf(ab0[1] - base0));
        CVT_PK(q1, __expf(ab0[2] - base0), __expf(ab0[3] - base0));
        CVT_PK(q2, __expf(ab1[0] - base0), __expf(ab1[1] - base0));
        CVT_PK(q3, __expf(ab1[2] - base0), __expf(ab1[3] - base0));
        union { unsigned w[4]; s16x8 v; } bu;
        bu.w[0] = q0; bu.w[1] = q1; bu.w[2] = q2; bu.w[3] = q3;
        Bf = bu.v;
    }

    f32x4 pl0, pl1, pl2, pl3, qh0, qh1, qh2, qh3;
    LOADSLOT(pl0, qh0, t_a + 1) LOADSLOT(pl1, qh1, t_a + 2)
    LOADSLOT(pl2, qh2, t_a + 3) LOADSLOT(pl3, qh3, t_a + 4)

    const f32x4 zz4 = {0.f, 0.f, 0.f, 0.f};
    int t = t_a + 1, k = 1;
    float uval = 0.0f;
    float v0save = 0.0f;              // alpha[0] at the checkpoint (s>0)
    float* vrow = snap + ((size_t)b * SEG_S + s) * CRF_C;

#define PSTEP(PL_, PH_)                                                        \
    {                                                                          \
        f32x4 xl = PL_, xh = PH_;                                              \
        { int tn_ = t + 4; if (tn_ > tend) tn_ = tend;                         \
          LOADSLOT(PL_, PH_, tn_) }                                            \
        f32x4 D0 = __builtin_amdgcn_mfma_f32_16x16x32_bf16(A0, Bf, zz4, 0, 0, 0); \
        f32x4 D1 = __builtin_amdgcn_mfma_f32_16x16x32_bf16(A1, Bf, zz4, 0, 0, 0); \
        int ex = (int)((__float_as_uint(D0[0]) >> 23) & 0xFFu) - 127;          \
        ex = __shfl(ex, r, 64);                                                \
        float me = (float)ex;                                                  \
        float Aent = A;                                                        \
        A = Aent + me * 0.69314718055994530942f;                               \
        float f0 = exp2f(fmaf(xl[0], 1.44269504088896f, -me));                 \
        float f1 = exp2f(fmaf(xl[1], 1.44269504088896f, -me));                 \
        float f2 = exp2f(fmaf(xl[2], 1.44269504088896f, -me));                 \
        float f3 = exp2f(fmaf(xl[3], 1.44269504088896f, -me));                 \
        float g0 = exp2f(fmaf(xh[0], 1.44269504088896f, -me));                 \
        float g1 = exp2f(fmaf(xh[1], 1.44269504088896f, -me));                 \
        float g2 = exp2f(fmaf(xh[2], 1.44269504088896f, -me));                 \
        float g3 = exp2f(fmaf(xh[3], 1.44269504088896f, -me));                 \
        if ((s != 0) && (k == WARM - 1)) {   /* wave-uniform checkpoint */     \
            f32x4 vlo, vhi;                                                    \
            vlo[0] = xl[0] + Aent + __logf(D0[0]);                             \
            vlo[1] = xl[1] + Aent + __logf(D0[1]);                             \
            vlo[2] = xl[2] + Aent + __logf(D0[2]);                             \
            vlo[3] = xl[3] + Aent + __logf(D0[3]);                             \
            vhi[0] = xh[0] + Aent + __logf(D1[0]);                             \
            vhi[1] = xh[1] + Aent + __logf(D1[1]);                             \
            vhi[2] = xh[2] + Aent + __logf(D1[2]);                             \
            vhi[3] = xh[3] + Aent + __logf(D1[3]);                             \
            *(f32x4*)(vrow + 4 * h) = vlo;                                     \
            *(f32x4*)(vrow + 16 + 4 * h) = vhi;                                \
            v0save = vlo[0];   /* register copy, all lanes, no divergence */   \
        }                                                                      \
        if (k == nsteps) uval = xl[0] + Aent + __logf(D0[0]);                  \
        unsigned w0, w1, w2, w3;                                               \
        CVT_PK(w0, D0[0] * f0, D0[1] * f1);                                    \
        CVT_PK(w1, D0[2] * f2, D0[3] * f3);                                    \
        CVT_PK(w2, D1[0] * g0, D1[1] * g1);                                    \
        CVT_PK(w3, D1[2] * g2, D1[3] * g3);                                    \
        SWAP32(w0, w2); SWAP16(w0, w2);                                        \
        SWAP32(w1, w3); SWAP16(w1, w3);                                        \
        {                                                                      \
            union { unsigned w[4]; s16x8 v; } bu_;                             \
            bu_.w[0] = w0; bu_.w[1] = w1; bu_.w[2] = w2; bu_.w[3] = w3;        \
            Bf = bu_.v;                                                        \
        }                                                                      \
        ++t; ++k;                                                              \
    }

    const int ngr = nsteps >> 2;    // nsteps in {7,11,15,19}, all == 3 mod 4
    for (int g = 0; g < ngr; ++g) {
        PSTEP(pl0, qh0) PSTEP(pl1, qh1) PSTEP(pl2, qh2) PSTEP(pl3, qh3)
    }
    PSTEP(pl0, qh0) PSTEP(pl1, qh1) PSTEP(pl2, qh2)
#undef PSTEP

    // h==0 store OUTSIDE the loop, transposed. g_s = u_s - v0_s (v0_0 = 0).
    if (h == 0) gg[(size_t)s * CRF_B + b] = uval - v0save;
}

// ============================================================================
// K2 (out, stitch fused): segment s writes rows [SL*s, SL*(s+1)).
// s>0: shift s0 = sum_{sp=0..s-1} gg[sp][b] — coalesced transposed scan with
// 4-way partial sums. State init p = exp(v[j]-v[0]) from snap.
// ============================================================================
template <int SL>
__global__ __launch_bounds__(64) void crf_out_kernel(
    const float* __restrict__ x, const float* __restrict__ trans,
    const float* __restrict__ orig, const float* __restrict__ snap,
    const float* __restrict__ gg, float* __restrict__ out)
{
    const int SEG_S = CRF_T / SL;
    const int l = threadIdx.x;
    const int r = l & 15;
    const int h = l >> 4;
    const int b = blockIdx.x * 16 + r;
    const int s = blockIdx.y;

    MAKE_AFRAGS();

    const float* xb = x + (size_t)b * CRF_T * CRF_C;

    int t0, nst;
    float s0;
    s16x8 Bf;
    if (s == 0) {
        t0 = 1; nst = SL - 1;
        s0 = xb[0] + orig[0];
        f32x4 ib0 = *(const f32x4*)(xb + 8 * h);
        f32x4 ib1 = *(const f32x4*)(xb + 8 * h + 4);
        f32x4 ob0 = *(const f32x4*)(orig + 8 * h);
        f32x4 ob1 = *(const f32x4*)(orig + 8 * h + 4);
        unsigned q0, q1, q2, q3;
        CVT_PK(q0, __expf(ib0[0] + ob0[0] - s0), __expf(ib0[1] + ob0[1] - s0));
        CVT_PK(q1, __expf(ib0[2] + ob0[2] - s0), __expf(ib0[3] + ob0[3] - s0));
        CVT_PK(q2, __expf(ib1[0] + ob1[0] - s0), __expf(ib1[1] + ob1[1] - s0));
        CVT_PK(q3, __expf(ib1[2] + ob1[2] - s0), __expf(ib1[3] + ob1[3] - s0));
        union { unsigned w[4]; s16x8 v; } bu;
        bu.w[0] = q0; bu.w[1] = q1; bu.w[2] = q2; bu.w[3] = q3;
        Bf = bu.v;
        // t = 0 outputs (D-layout)
        f32x4 xd0 = *(const f32x4*)(xb + 4 * h);
        f32x4 xd1 = *(const f32x4*)(xb + 16 + 4 * h);
        f32x4 od0 = *(const f32x4*)(orig + 4 * h);
        f32x4 od1 = *(const f32x4*)(orig + 16 + 4 * h);
        f32x4 a00, a01;
        #pragma unroll
        for (int i = 0; i < 4; ++i) { a00[i] = xd0[i] + od0[i]; a01[i] = xd1[i] + od1[i]; }
        *(f32x4*)(out + (size_t)b * CRF_C + 4 * h) = a00;
        *(f32x4*)(out + (size_t)b * CRF_C + 16 + 4 * h) = a01;
    } else {
        t0 = SL * s; nst = SL;
        // coalesced prefix of g: s0 = sum_{sp=0..s-1} gg[sp][b]
        const float* gb = gg + b;
        float c0 = 0.f, c1 = 0.f, c2 = 0.f, c3 = 0.f;
        int sp = 0;
        for (; sp + 4 <= s; sp += 4) {
            c0 += gb[(size_t)(sp)     * CRF_B];
            c1 += gb[(size_t)(sp + 1) * CRF_B];
            c2 += gb[(size_t)(sp + 2) * CRF_B];
            c3 += gb[(size_t)(sp + 3) * CRF_B];
        }
        for (; sp < s; ++sp) c0 += gb[(size_t)sp * CRF_B];
        s0 = (c0 + c1) + (c2 + c3);

        const float* vp = snap + ((size_t)b * SEG_S + s) * CRF_C;
        const float vp0 = vp[0];
        f32x4 vb0 = *(const f32x4*)(vp + 8 * h);
        f32x4 vb1 = *(const f32x4*)(vp + 8 * h + 4);
        unsigned q0, q1, q2, q3;
        CVT_PK(q0, __expf(vb0[0] - vp0), __expf(vb0[1] - vp0));
        CVT_PK(q1, __expf(vb0[2] - vp0), __expf(vb0[3] - vp0));
        CVT_PK(q2, __expf(vb1[0] - vp0), __expf(vb1[1] - vp0));
        CVT_PK(q3, __expf(vb1[2] - vp0), __expf(vb1[3] - vp0));
        union { unsigned w[4]; s16x8 v; } bu;
        bu.w[0] = q0; bu.w[1] = q1; bu.w[2] = q2; bu.w[3] = q3;
        Bf = bu.v;
    }
    const int tendo = SL * s + SL - 1;   // last x row this block needs

    f32x4 pl0, pl1, pl2, pl3, qh0, qh1, qh2, qh3;
    LOADSLOT(pl0, qh0, t0)     LOADSLOT(pl1, qh1, t0 + 1)
    LOADSLOT(pl2, qh2, t0 + 2) LOADSLOT(pl3, qh3, t0 + 3)

    const f32x4 zz4 = {0.f, 0.f, 0.f, 0.f};
    float sU = s0, sC = s0, aQ = s0;
    float* op0 = out + ((size_t)t0 * CRF_B + b) * CRF_C + 4 * h;
    int t = t0;

#define STEP(PL_, PH_)                                                         \
    {                                                                          \
        f32x4 xl = PL_, xh = PH_;                                              \
        { int tn_ = t + 4; if (tn_ > tendo) tn_ = tendo;                       \
          LOADSLOT(PL_, PH_, tn_) }                                            \
        f32x4 D0 = __builtin_amdgcn_mfma_f32_16x16x32_bf16(A0, Bf, zz4, 0, 0, 0); \
        f32x4 D1 = __builtin_amdgcn_mfma_f32_16x16x32_bf16(A1, Bf, zz4, 0, 0, 0); \
        float dlt = sU - sC;                                                   \
        float f0 = __expf(xl[0] + dlt), f1 = __expf(xl[1] + dlt);              \
        float f2 = __expf(xl[2] + dlt), f3 = __expf(xl[3] + dlt);              \
        float g0 = __expf(xh[0] + dlt), g1 = __expf(xh[1] + dlt);              \
        float g2 = __expf(xh[2] + dlt), g3 = __expf(xh[3] + dlt);              \
        f32x4 alo, ahi;                                                        \
        alo[0] = xl[0] + sU + __logf(D0[0]);                                   \
        alo[1] = xl[1] + sU + __logf(D0[1]);                                   \
        alo[2] = xl[2] + sU + __logf(D0[2]);                                   \
        alo[3] = xl[3] + sU + __logf(D0[3]);                                   \
        ahi[0] = xh[0] + sU + __logf(D1[0]);                                   \
        ahi[1] = xh[1] + sU + __logf(D1[1]);                                   \
        ahi[2] = xh[2] + sU + __logf(D1[2]);                                   \
        ahi[3] = xh[3] + sU + __logf(D1[3]);                                   \
        *(f32x4*)op0 = alo;                                                    \
        *(f32x4*)(op0 + 16) = ahi;                                             \
        op0 += (size_t)CRF_B * CRF_C;                                          \
        float a0new = __shfl(alo[0], r, 64);                                   \
        unsigned w0, w1, w2, w3;                                               \
        CVT_PK(w0, D0[0] * f0, D0[1] * f1);                                    \
        CVT_PK(w1, D0[2] * f2, D0[3] * f3);                                    \
        CVT_PK(w2, D1[0] * g0, D1[1] * g1);                                    \
        CVT_PK(w3, D1[2] * g2, D1[3] * g3);                                    \
        SWAP32(w0, w2); SWAP16(w0, w2);                                        \
        SWAP32(w1, w3); SWAP16(w1, w3);                                        \
        {                                                                      \
            union { unsigned w[4]; s16x8 v; } bu_;                             \
            bu_.w[0] = w0; bu_.w[1] = w1; bu_.w[2] = w2; bu_.w[3] = w3;        \
            Bf = bu_.v;                                                        \
        }                                                                      \
        sU = sC; sC = aQ; aQ = a0new;                                          \
        ++t;                                                                   \
    }

    const int ngr = nst >> 2;
    for (int g = 0; g < ngr; ++g) {
        STEP(pl0, qh0) STEP(pl1, qh1) STEP(pl2, qh2) STEP(pl3, qh3)
    }
    if (nst & 3) {    // tail is 0 or 3
        STEP(pl0, qh0) STEP(pl1, qh1) STEP(pl2, qh2)
    }
#undef STEP
}

// ============================================================================
// Fallback (round-5 single-kernel, validated) — used only if ws too small.
// ============================================================================
__global__ __launch_bounds__(64) void crf_fwd_fallback(
    const float* __restrict__ x, const float* __restrict__ trans,
    const float* __restrict__ orig, float* __restrict__ out)
{
    const int l = threadIdx.x;
    const int r = l & 15;
    const int h = l >> 4;
    const int b = blockIdx.x * 16 + r;

    MAKE_AFRAGS();

    const float* xb = x + (size_t)b * CRF_T * CRF_C;
    float s0 = xb[0] + orig[0];

    f32x4 ib0 = *(const f32x4*)(xb + 8 * h);
    f32x4 ib1 = *(const f32x4*)(xb + 8 * h + 4);
    f32x4 ob0 = *(const f32x4*)(orig + 8 * h);
    f32x4 ob1 = *(const f32x4*)(orig + 8 * h + 4);
    unsigned q0, q1, q2, q3;
    CVT_PK(q0, __expf(ib0[0] + ob0[0] - s0), __expf(ib0[1] + ob0[1] - s0));
    CVT_PK(q1, __expf(ib0[2] + ob0[2] - s0), __expf(ib0[3] + ob0[3] - s0));
    CVT_PK(q2, __expf(ib1[0] + ob1[0] - s0), __expf(ib1[1] + ob1[1] - s0));
    CVT_PK(q3, __expf(ib1[2] + ob1[2] - s0), __expf(ib1[3] + ob1[3] - s0));
    s16x8 Bf;
    {
        union { unsigned w[4]; s16x8 v; } bu;
        bu.w[0] = q0; bu.w[1] = q1; bu.w[2] = q2; bu.w[3] = q3;
        Bf = bu.v;
    }
    {
        f32x4 xd0 = *(const f32x4*)(xb + 4 * h);
        f32x4 xd1 = *(const f32x4*)(xb + 16 + 4 * h);
        f32x4 od0 = *(const f32x4*)(orig + 4 * h);
        f32x4 od1 = *(const f32x4*)(orig + 16 + 4 * h);
        f32x4 a00, a01;
        #pragma unroll
        for (int i = 0; i < 4; ++i) { a00[i] = xd0[i] + od0[i]; a01[i] = xd1[i] + od1[i]; }
        *(f32x4*)(out + (size_t)b * CRF_C + 4 * h) = a00;
        *(f32x4*)(out + (size_t)b * CRF_C + 16 + 4 * h) = a01;
    }

    f32x4 pl0, pl1, pl2, pl3, qh0, qh1, qh2, qh3;
    LOADSLOT(pl0, qh0, 1) LOADSLOT(pl1, qh1, 2)
    LOADSLOT(pl2, qh2, 3) LOADSLOT(pl3, qh3, 4)

    const f32x4 zz4 = {0.f, 0.f, 0.f, 0.f};
    float sU = s0, sC = s0, aQ = s0;
    float* op0 = out + ((size_t)CRF_B + b) * CRF_C + 4 * h;
    int t = 1;

#define STEP(PL_, PH_)                                                         \
    {                                                                          \
        f32x4 xl = PL_, xh = PH_;                                              \
        { int tn_ = t + 4; if (tn_ > CRF_T - 1) tn_ = CRF_T - 1;               \
          LOADSLOT(PL_, PH_, tn_) }                                            \
        f32x4 D0 = __builtin_amdgcn_mfma_f32_16x16x32_bf16(A0, Bf, zz4, 0, 0, 0); \
        f32x4 D1 = __builtin_amdgcn_mfma_f32_16x16x32_bf16(A1, Bf, zz4, 0, 0, 0); \
        float dlt = sU - sC;                                                   \
        float f0 = __expf(xl[0] + dlt), f1 = __expf(xl[1] + dlt);              \
        float f2 = __expf(xl[2] + dlt), f3 = __expf(xl[3] + dlt);              \
        float g0 = __expf(xh[0] + dlt), g1 = __expf(xh[1] + dlt);              \
        float g2 = __expf(xh[2] + dlt), g3 = __expf(xh[3] + dlt);              \
        f32x4 alo, ahi;                                                        \
        alo[0] = xl[0] + sU + __logf(D0[0]);                                   \
        alo[1] = xl[1] + sU + __logf(D0[1]);                                   \
        alo[2] = xl[2] + sU + __logf(D0[2]);                                   \
        alo[3] = xl[3] + sU + __logf(D0[3]);                                   \
        ahi[0] = xh[0] + sU + __logf(D1[0]);                                   \
        ahi[1] = xh[1] + sU + __logf(D1[1]);                                   \
        ahi[2] = xh[2] + sU + __logf(D1[2]);                                   \
        ahi[3] = xh[3] + sU + __logf(D1[3]);                                   \
        *(f32x4*)op0 = alo;                                                    \
        *(f32x4*)(op0 + 16) = ahi;                                             \
        op0 += (size_t)CRF_B * CRF_C;                                          \
        float a0new = __shfl(alo[0], r, 64);                                   \
        unsigned w0, w1, w2, w3;                                               \
        CVT_PK(w0, D0[0] * f0, D0[1] * f1);                                    \
        CVT_PK(w1, D0[2] * f2, D0[3] * f3);                                    \
        CVT_PK(w2, D1[0] * g0, D1[1] * g1);                                    \
        CVT_PK(w3, D1[2] * g2, D1[3] * g3);                                    \
        SWAP32(w0, w2); SWAP16(w0, w2);                                        \
        SWAP32(w1, w3); SWAP16(w1, w3);                                        \
        {                                                                      \
            union { unsigned w[4]; s16x8 v; } bu_;                             \
            bu_.w[0] = w0; bu_.w[1] = w1; bu_.w[2] = w2; bu_.w[3] = w3;        \
            Bf = bu_.v;                                                        \
        }                                                                      \
        sU = sC; sC = aQ; aQ = a0new;                                          \
        ++t;                                                                   \
    }

    for (int g = 0; g < 127; ++g) {   // 508 steps
        STEP(pl0, qh0) STEP(pl1, qh1) STEP(pl2, qh2) STEP(pl3, qh3)
    }
    STEP(pl0, qh0) STEP(pl1, qh1) STEP(pl2, qh2)   // 511 total
#undef STEP
}

extern "C" void kernel_launch(void* const* d_in, const int* in_sizes, int n_in,
                              void* d_out, int out_size, void* d_ws, size_t ws_size,
                              hipStream_t stream) {
    const float* pad_x = (const float*)d_in[0];
    const float* trans = (const float*)d_in[1];
    const float* orig  = (const float*)d_in[2];
    float* out = (float*)d_out;

    // ws layout: snap[B][SEG_S][32] f32, gg[SEG_S][B] f32.
    // need(SL) = B * (512/SL) * 33 * 4 bytes.
    auto need = [](int SL) {
        return (size_t)CRF_B * (CRF_T / SL) * (CRF_C + 1) * sizeof(float);
    };

    if (ws_size >= need(8)) {            // SEG_S=64, ~8.7 MB  (top tier)
        const int SEG_S = CRF_T / 8;
        float* snap = (float*)d_ws;
        float* gg   = snap + (size_t)CRF_B * SEG_S * CRF_C;
        crf_seam_kernel<8><<<dim3(CRF_B / 16, SEG_S), dim3(64), 0, stream>>>(
            pad_x, trans, orig, snap, gg);
        crf_out_kernel<8><<<dim3(CRF_B / 16, SEG_S), dim3(64), 0, stream>>>(
            pad_x, trans, orig, snap, gg, out);
    } else if (ws_size >= need(16)) {    // SEG_S=32, ~4.3 MB
        const int SEG_S = CRF_T / 16;
        float* snap = (float*)d_ws;
        float* gg   = snap + (size_t)CRF_B * SEG_S * CRF_C;
        crf_seam_kernel<16><<<dim3(CRF_B / 16, SEG_S), dim3(64), 0, stream>>>(
            pad_x, trans, orig, snap, gg);
        crf_out_kernel<16><<<dim3(CRF_B / 16, SEG_S), dim3(64), 0, stream>>>(
            pad_x, trans, orig, snap, gg, out);
    } else {
        crf_fwd_fallback<<<dim3(CRF_B / 16), dim3(64), 0, stream>>>(
            pad_x, trans, orig, out);
    }
}